// Round 2
// baseline (402.681 us; speedup 1.0000x reference)
//
#include <hip/hip_runtime.h>
#include <cmath>

// ---------------- problem constants ----------------
#define M_ROWS   11520      // 2*5760
#define DIM      512
#define HID      1960
#define HIDP     2048       // padded HID (zeros)
#define OH       20
#define OW       36
#define LVEC     720        // OH*OW
#define NCH      40         // HID/49
#define BPRIME   16         // M_ROWS / LVEC
#define HP       66         // 60 + 2*3
#define WP       114        // 108 + 2*3

typedef unsigned short u16;
typedef __bf16 bf16x8 __attribute__((ext_vector_type(8)));
typedef float  f32x4  __attribute__((ext_vector_type(4)));

__device__ __forceinline__ u16 f2bf(float f) {
    unsigned u = __float_as_uint(f);
    u += 0x7fffu + ((u >> 16) & 1u);   // RNE
    return (u16)(u >> 16);
}
__device__ __forceinline__ float bf2f(u16 h) {
    return __uint_as_float(((unsigned)h) << 16);
}

__device__ __forceinline__ void gload_lds16(const void* g, void* l) {
    __builtin_amdgcn_global_load_lds(
        (const __attribute__((address_space(1))) void*)g,
        (__attribute__((address_space(3))) void*)l, 16, 0, 0);
}

// ---------------- fp32 -> bf16 converts ----------------
__global__ __launch_bounds__(256) void cvt_x(const float* __restrict__ src,
                                             u16* __restrict__ dst, int n) {
    int i = (blockIdx.x * 256 + threadIdx.x) * 4;
    if (i < n) {
        float4 v = *(const float4*)(src + i);
        ushort4 o;
        o.x = f2bf(v.x); o.y = f2bf(v.y); o.z = f2bf(v.z); o.w = f2bf(v.w);
        *(ushort4*)(dst + i) = o;
    }
}

// W1: (1960,512) -> (2048,512), pad rows with zero
__global__ __launch_bounds__(256) void cvt_w1(const float* __restrict__ src,
                                              u16* __restrict__ dst) {
    int i = (blockIdx.x * 256 + threadIdx.x) * 4;   // over 2048*512
    ushort4 o;
    if (i < HID * DIM) {
        float4 v = *(const float4*)(src + i);
        o.x = f2bf(v.x); o.y = f2bf(v.y); o.z = f2bf(v.z); o.w = f2bf(v.w);
    } else {
        o.x = o.y = o.z = o.w = 0;
    }
    *(ushort4*)(dst + i) = o;
}

// W2: (512,1960) -> (512,2048), pad cols with zero. 1960 % 4 == 0.
__global__ __launch_bounds__(256) void cvt_w2(const float* __restrict__ src,
                                              u16* __restrict__ dst) {
    int i = (blockIdx.x * 256 + threadIdx.x) * 4;   // over 512*2048
    int d = i / HIDP, c = i % HIDP;
    ushort4 o;
    if (c < HID) {
        float4 v = *(const float4*)(src + d * HID + c);
        o.x = f2bf(v.x); o.y = f2bf(v.y); o.z = f2bf(v.z); o.w = f2bf(v.w);
    } else {
        o.x = o.y = o.z = o.w = 0;
    }
    *(ushort4*)(dst + i) = o;
}

// ---------------- bf16 NT-GEMM: C[m,n] = sum_k A[m,k]*B[n,k] + bias[n] ----------------
// 128(M) x BN(N) tile, BK=64, 4 waves (2x2), each wave 64 x BN/2 via
// mfma_f32_16x16x32_bf16. LDS staged with global_load_lds width 16; XOR swizzle
// applied on the GLOBAL side (LDS dest is wave-uniform+lane*16) so ds_read_b128
// is bank-conflict-free.
template <int OUT_BF16, int BN>
__global__ __launch_bounds__(256) void gemm_bt(const u16* __restrict__ A,
                                               const u16* __restrict__ B,
                                               const float* __restrict__ bias,
                                               int biasN, void* __restrict__ Cout,
                                               int N, int K) {
    constexpr int WN = BN / 2;     // wave N extent
    constexpr int NU = WN / 16;    // acc tiles along N

    __shared__ u16 sA[128 * 64];
    __shared__ u16 sB[BN * 64];

    const int tid  = threadIdx.x;
    const int ntn  = N / BN;
    const int bm   = blockIdx.x / ntn;
    const int bn   = blockIdx.x % ntn;
    const int lane = tid & 63;
    const int wv   = tid >> 6;
    const int wm   = (wv >> 1) * 64;
    const int wn   = (wv & 1) * WN;
    const int r    = lane & 15;
    const int quad = lane >> 4;

    const size_t Arow0 = (size_t)bm * 128 * K;
    const size_t Brow0 = (size_t)bn * BN * K;

    f32x4 acc[4][NU] = {};

    for (int kt = 0; kt < K; kt += 64) {
        __syncthreads();
#pragma unroll
        for (int i = 0; i < 4; i++) {
            int e   = i * 256 + tid;       // 16B chunk id within A tile
            int row = e >> 3;              // 8 chunks per 128B row
            int cp  = e & 7;
            int cg  = cp ^ (row & 7);      // global chunk fetched into LDS slot cp
            gload_lds16(A + Arow0 + (size_t)row * K + kt + cg * 8, (char*)sA + e * 16);
        }
#pragma unroll
        for (int i = 0; i < (BN * 8) / 256; i++) {
            int e   = i * 256 + tid;
            int row = e >> 3;
            int cp  = e & 7;
            int cg  = cp ^ (row & 7);
            gload_lds16(B + Brow0 + (size_t)row * K + kt + cg * 8, (char*)sB + e * 16);
        }
        __syncthreads();
#pragma unroll
        for (int kk = 0; kk < 2; kk++) {
            bf16x8 af[4], bg[NU];
#pragma unroll
            for (int t = 0; t < 4; t++) {
                int row = wm + t * 16 + r;
                int c   = (kk * 4 + quad) ^ (row & 7);
                af[t] = *(const bf16x8*)(sA + row * 64 + c * 8);
            }
#pragma unroll
            for (int u = 0; u < NU; u++) {
                int row = wn + u * 16 + r;
                int c   = (kk * 4 + quad) ^ (row & 7);
                bg[u] = *(const bf16x8*)(sB + row * 64 + c * 8);
            }
#pragma unroll
            for (int t = 0; t < 4; t++)
#pragma unroll
                for (int u = 0; u < NU; u++)
                    acc[t][u] = __builtin_amdgcn_mfma_f32_16x16x32_bf16(
                        af[t], bg[u], acc[t][u], 0, 0, 0);
        }
    }

    // epilogue: C/D layout col = lane&15 (n), row = quad*4+q (m)
    const int gm0 = bm * 128 + wm;
    const int gn0 = bn * BN + wn;
#pragma unroll
    for (int u = 0; u < NU; u++) {
        int gn = gn0 + u * 16 + r;
        float bv = (gn < biasN) ? bias[gn] : 0.0f;
#pragma unroll
        for (int t = 0; t < 4; t++) {
            int gm = gm0 + t * 16 + quad * 4;
#pragma unroll
            for (int q = 0; q < 4; q++) {
                float v = acc[t][u][q] + bv;
                if (OUT_BF16)
                    ((u16*)Cout)[(size_t)(gm + q) * N + gn] = f2bf(v);
                else
                    ((float*)Cout)[(size_t)(gm + q) * N + gn] = v;
            }
        }
    }
}

// ---------------- fold -> /norm -> crop+repad -> unfold -> gelu, in place ----------------
// One block per (b', ch). Fold is a SCATTER: each h element (l,k) maps to exactly
// one padded pixel (ky+3oy, kx+3ox) -> coalesced global reads + LDS atomicAdd.
// Then normalize (/count, crop borders to 0), then unfold+gelu with coalesced
// writes over the same global region (block-local, barrier-separated -> in-place
// is race-free).
__global__ __launch_bounds__(256) void mid_fold_unfold(u16* __restrict__ hg) {
    __shared__ float f[HP * WP];   // 66*114*4 = 30096 B

    const int bp = blockIdx.x / NCH;
    const int ch = blockIdx.x % NCH;
    const int n0 = bp * LVEC;
    const int c0 = ch * 49;
    const int tid = threadIdx.x;

    for (int p = tid; p < HP * WP; p += 256) f[p] = 0.0f;
    __syncthreads();

    // scatter-fold: coalesced reads (49 contiguous u16 per row)
    for (int i = tid; i < 49 * LVEC; i += 256) {
        int l = i / 49, k = i - l * 49;
        int ky = k / 7, kx = k - ky * 7;
        int oy = l / OW, ox = l - oy * OW;
        float v = bf2f(hg[(size_t)(n0 + l) * HIDP + c0 + k]);
        atomicAdd(&f[(ky + 3 * oy) * WP + (kx + 3 * ox)], v);
    }
    __syncthreads();

    // normalize + crop+repad (borders outside [3,62]x[3,110] become 0)
    for (int p = tid; p < HP * WP; p += 256) {
        int py = p / WP, px = p - (p / WP) * WP;
        float val = 0.0f;
        if (py >= 3 && py <= 62 && px >= 3 && px <= 110) {
            int cy = 0, cx = 0;
            for (int ky = py % 3; ky <= 6; ky += 3)
                if (py - ky >= 0 && py - ky <= 57) cy++;
            for (int kx = px % 3; kx <= 6; kx += 3)
                if (px - kx >= 0 && px - kx <= 105) cx++;
            val = f[p] / (float)(cy * cx);
        }
        __syncthreads();   // all reads of f done before overwrite
        f[p] = val;
    }
    __syncthreads();

    // unfold + gelu + coalesced write-back
    for (int i = tid; i < 49 * LVEC; i += 256) {
        int l = i / 49, k = i - l * 49;
        int ky = k / 7, kx = k - ky * 7;
        int oy = l / OW, ox = l - oy * OW;
        float v = f[(ky + 3 * oy) * WP + (kx + 3 * ox)];
        float g = 0.5f * v * (1.0f + erff(v * 0.70710678118654752f));  // exact gelu
        hg[(size_t)(n0 + l) * HIDP + c0 + k] = f2bf(g);
    }
}

// ---------------- launch ----------------
extern "C" void kernel_launch(void* const* d_in, const int* in_sizes, int n_in,
                              void* d_out, int out_size, void* d_ws, size_t ws_size,
                              hipStream_t stream) {
    (void)in_sizes; (void)n_in; (void)out_size; (void)ws_size;
    const float* x  = (const float*)d_in[0];
    const float* W1 = (const float*)d_in[1];
    const float* b1 = (const float*)d_in[2];
    const float* W2 = (const float*)d_in[3];
    const float* b2 = (const float*)d_in[4];
    float* out = (float*)d_out;

    char* ws = (char*)d_ws;
    u16* xb  = (u16*)(ws);                                   // 11520*512*2  = 11,796,480
    u16* W1b = (u16*)(ws + 11796480);                        // 2048*512*2   =  2,097,152
    u16* W2b = (u16*)(ws + 11796480 + 2097152);              // 512*2048*2   =  2,097,152
    u16* hg  = (u16*)(ws + 11796480 + 2097152 + 2097152);    // 11520*2048*2 = 47,185,920

    // converts
    cvt_x <<<(M_ROWS * DIM) / (256 * 4), 256, 0, stream>>>(x, xb, M_ROWS * DIM);
    cvt_w1<<<(HIDP * DIM) / (256 * 4), 256, 0, stream>>>(W1, W1b);
    cvt_w2<<<(DIM * HIDP) / (256 * 4), 256, 0, stream>>>(W2, W2b);

    // GEMM1: h = x @ W1^T + b1  -> bf16 (11520 x 2048, cols >=1960 are zero)
    gemm_bt<1, 128><<<(M_ROWS / 128) * (HIDP / 128), 256, 0, stream>>>(
        xb, W1b, b1, HID, (void*)hg, HIDP, DIM);

    // middle: fold / norm / unfold / gelu, in place on hg
    mid_fold_unfold<<<BPRIME * NCH, 256, 0, stream>>>(hg);

    // GEMM2: out = g @ W2^T + b2 -> fp32 (11520 x 512), 128x64 tiles for 720 blocks
    gemm_bt<0, 64><<<(M_ROWS / 128) * (DIM / 64), 256, 0, stream>>>(
        hg, W2b, b2, DIM, (void*)out, DIM, HIDP);
}

// Round 3
// 277.279 us; speedup vs baseline: 1.4523x; 1.4523x over previous
//
#include <hip/hip_runtime.h>
#include <cmath>

// ---------------- problem constants ----------------
#define M_ROWS   11520      // 2*5760
#define DIM      512
#define HID      1960
#define HIDP     2048       // padded HID (zeros)
#define OH       20
#define OW       36
#define LVEC     720        // OH*OW
#define NCH      40         // HID/49
#define BPRIME   16         // M_ROWS / LVEC
#define HP       66         // 60 + 2*3
#define WP       114        // 108 + 2*3

typedef unsigned short u16;
typedef __bf16 bf16x8 __attribute__((ext_vector_type(8)));
typedef float  f32x4  __attribute__((ext_vector_type(4)));

__device__ __forceinline__ u16 f2bf(float f) {
    unsigned u = __float_as_uint(f);
    u += 0x7fffu + ((u >> 16) & 1u);   // RNE
    return (u16)(u >> 16);
}
__device__ __forceinline__ float bf2f(u16 h) {
    return __uint_as_float(((unsigned)h) << 16);
}

__device__ __forceinline__ void gload_lds16(const void* g, void* l) {
    __builtin_amdgcn_global_load_lds(
        (const __attribute__((address_space(1))) void*)g,
        (__attribute__((address_space(3))) void*)l, 16, 0, 0);
}

// ---------------- fp32 -> bf16 converts ----------------
__global__ __launch_bounds__(256) void cvt_x(const float* __restrict__ src,
                                             u16* __restrict__ dst, int n) {
    int i = (blockIdx.x * 256 + threadIdx.x) * 4;
    if (i < n) {
        float4 v = *(const float4*)(src + i);
        ushort4 o;
        o.x = f2bf(v.x); o.y = f2bf(v.y); o.z = f2bf(v.z); o.w = f2bf(v.w);
        *(ushort4*)(dst + i) = o;
    }
}

// W1: (1960,512) -> (2048,512), pad rows with zero
__global__ __launch_bounds__(256) void cvt_w1(const float* __restrict__ src,
                                              u16* __restrict__ dst) {
    int i = (blockIdx.x * 256 + threadIdx.x) * 4;   // over 2048*512
    ushort4 o;
    if (i < HID * DIM) {
        float4 v = *(const float4*)(src + i);
        o.x = f2bf(v.x); o.y = f2bf(v.y); o.z = f2bf(v.z); o.w = f2bf(v.w);
    } else {
        o.x = o.y = o.z = o.w = 0;
    }
    *(ushort4*)(dst + i) = o;
}

// W2: (512,1960) -> (512,2048), pad cols with zero. 1960 % 4 == 0.
__global__ __launch_bounds__(256) void cvt_w2(const float* __restrict__ src,
                                              u16* __restrict__ dst) {
    int i = (blockIdx.x * 256 + threadIdx.x) * 4;   // over 512*2048
    int d = i / HIDP, c = i % HIDP;
    ushort4 o;
    if (c < HID) {
        float4 v = *(const float4*)(src + d * HID + c);
        o.x = f2bf(v.x); o.y = f2bf(v.y); o.z = f2bf(v.z); o.w = f2bf(v.w);
    } else {
        o.x = o.y = o.z = o.w = 0;
    }
    *(ushort4*)(dst + i) = o;
}

// ---------------- bf16 NT-GEMM: C[m,n] = sum_k A[m,k]*B[n,k] + bias[n] ----------------
// 128(M) x BN(N) tile, BK=64, 4 waves (2x2), each wave 64 x BN/2 via
// mfma_f32_16x16x32_bf16. LDS staged with global_load_lds width 16; XOR swizzle
// applied on the GLOBAL side (LDS dest is wave-uniform+lane*16) so ds_read_b128
// is bank-conflict-free.
template <int OUT_BF16, int BN>
__global__ __launch_bounds__(256) void gemm_bt(const u16* __restrict__ A,
                                               const u16* __restrict__ B,
                                               const float* __restrict__ bias,
                                               int biasN, void* __restrict__ Cout,
                                               int N, int K) {
    constexpr int WN = BN / 2;     // wave N extent
    constexpr int NU = WN / 16;    // acc tiles along N

    __shared__ u16 sA[128 * 64];
    __shared__ u16 sB[BN * 64];

    const int tid  = threadIdx.x;
    const int ntn  = N / BN;
    const int bm   = blockIdx.x / ntn;
    const int bn   = blockIdx.x % ntn;
    const int lane = tid & 63;
    const int wv   = tid >> 6;
    const int wm   = (wv >> 1) * 64;
    const int wn   = (wv & 1) * WN;
    const int r    = lane & 15;
    const int quad = lane >> 4;

    const size_t Arow0 = (size_t)bm * 128 * K;
    const size_t Brow0 = (size_t)bn * BN * K;

    f32x4 acc[4][NU] = {};

    for (int kt = 0; kt < K; kt += 64) {
        __syncthreads();
#pragma unroll
        for (int i = 0; i < 4; i++) {
            int e   = i * 256 + tid;       // 16B chunk id within A tile
            int row = e >> 3;              // 8 chunks per 128B row
            int cp  = e & 7;
            int cg  = cp ^ (row & 7);      // global chunk fetched into LDS slot cp
            gload_lds16(A + Arow0 + (size_t)row * K + kt + cg * 8, (char*)sA + e * 16);
        }
#pragma unroll
        for (int i = 0; i < (BN * 8) / 256; i++) {
            int e   = i * 256 + tid;
            int row = e >> 3;
            int cp  = e & 7;
            int cg  = cp ^ (row & 7);
            gload_lds16(B + Brow0 + (size_t)row * K + kt + cg * 8, (char*)sB + e * 16);
        }
        __syncthreads();
#pragma unroll
        for (int kk = 0; kk < 2; kk++) {
            bf16x8 af[4], bg[NU];
#pragma unroll
            for (int t = 0; t < 4; t++) {
                int row = wm + t * 16 + r;
                int c   = (kk * 4 + quad) ^ (row & 7);
                af[t] = *(const bf16x8*)(sA + row * 64 + c * 8);
            }
#pragma unroll
            for (int u = 0; u < NU; u++) {
                int row = wn + u * 16 + r;
                int c   = (kk * 4 + quad) ^ (row & 7);
                bg[u] = *(const bf16x8*)(sB + row * 64 + c * 8);
            }
#pragma unroll
            for (int t = 0; t < 4; t++)
#pragma unroll
                for (int u = 0; u < NU; u++)
                    acc[t][u] = __builtin_amdgcn_mfma_f32_16x16x32_bf16(
                        af[t], bg[u], acc[t][u], 0, 0, 0);
        }
    }

    // epilogue: C/D layout col = lane&15 (n), row = quad*4+q (m)
    const int gm0 = bm * 128 + wm;
    const int gn0 = bn * BN + wn;
#pragma unroll
    for (int u = 0; u < NU; u++) {
        int gn = gn0 + u * 16 + r;
        float bv = (gn < biasN) ? bias[gn] : 0.0f;
#pragma unroll
        for (int t = 0; t < 4; t++) {
            int gm = gm0 + t * 16 + quad * 4;
#pragma unroll
            for (int q = 0; q < 4; q++) {
                float v = acc[t][u][q] + bv;
                if (OUT_BF16)
                    ((u16*)Cout)[(size_t)(gm + q) * N + gn] = f2bf(v);
                else
                    ((float*)Cout)[(size_t)(gm + q) * N + gn] = v;
            }
        }
    }
}

// ---------------- midA: fold + normalize + crop -> P (bf16 padded image) ----------------
// One block per (b', ch, half). Loads 12 oy-rows of h (coalesced, independent) into
// LDS, then gathers <=9 LDS values per padded pixel (no atomics), normalizes,
// crops borders to zero, writes P rows [3*o0, 3*o0+33]. Halves overlap on P rows
// 30..33 with bit-identical values (same summation order) -> benign double write.
__global__ __launch_bounds__(256) void midA_fold(const u16* __restrict__ hg,
                                                 u16* __restrict__ P) {
    __shared__ u16 sh[12 * OW * 49];   // 21168 u16 = 42336 B

    const int b  = blockIdx.x;
    const int bp = b / (NCH * 2);
    const int rr = b - bp * (NCH * 2);
    const int ch = rr >> 1;
    const int s  = rr & 1;
    const int o0 = s * 10;             // first owned oy
    const int lo = s * 8;              // first loaded oy (0 or 8)
    const int n0 = bp * LVEC;
    const int c0 = ch * 49;
    const int tid = threadIdx.x;

    // phase 0: coalesced load of 12 token-rows x 49 channels
    for (int i = tid; i < 12 * OW * 49; i += 256) {
        int l = i / 49, k = i - l * 49;
        sh[i] = hg[(size_t)(n0 + lo * OW + l) * HIDP + c0 + k];
    }
    __syncthreads();

    // phase 1: gather-fold 34 pixel rows [3*o0 .. 3*o0+33]
    u16* Pb = P + (size_t)(bp * NCH + ch) * (HP * WP) + 3 * o0 * WP;
    for (int p = tid; p < 34 * WP; p += 256) {
        int pyr = p / WP;
        int px  = p - pyr * WP;
        int py  = pyr + 3 * o0;        // absolute padded row
        float val = 0.0f;
        if (py >= 3 && py <= 62 && px >= 3 && px <= 110) {
            int ky0 = py % 3, kx0 = px % 3;
            int cy = 0, cx = 0;
            float sum = 0.0f;
#pragma unroll
            for (int dy = 0; dy < 3; dy++) {
                int ky = ky0 + 3 * dy, ry = py - ky;
                if (ky <= 6 && ry >= 0 && ry <= 57) cy++;
            }
#pragma unroll
            for (int dx = 0; dx < 3; dx++) {
                int kx = kx0 + 3 * dx, rx = px - kx;
                if (kx <= 6 && rx >= 0 && rx <= 105) cx++;
            }
#pragma unroll
            for (int dy = 0; dy < 3; dy++) {
                int ky = ky0 + 3 * dy, ry = py - ky;
                bool vy = (ky <= 6 && ry >= 0 && ry <= 57);
                int lrow = ry / 3 - lo;
#pragma unroll
                for (int dx = 0; dx < 3; dx++) {
                    int kx = kx0 + 3 * dx, rx = px - kx;
                    if (vy && kx <= 6 && rx >= 0 && rx <= 105) {
                        int ox = rx / 3;
                        sum += bf2f(sh[(lrow * OW + ox) * 49 + ky * 7 + kx]);
                    }
                }
            }
            val = sum / (float)(cy * cx);
        }
        Pb[p] = f2bf(val);
    }
}

// ---------------- midB: unfold + gelu, in place over hg ----------------
// One block per (b', ch). Reads only P (no hg reads) -> in-place write is safe.
__global__ __launch_bounds__(256) void midB_unfold(const u16* __restrict__ P,
                                                   u16* __restrict__ hg) {
    __shared__ u16 sP[HP * WP];        // 7524 u16 = 15048 B

    const int b  = blockIdx.x;
    const int bp = b / NCH;
    const int ch = b - bp * NCH;
    const int n0 = bp * LVEC;
    const int c0 = ch * 49;
    const int tid = threadIdx.x;

    const u16* Pb = P + (size_t)(bp * NCH + ch) * (HP * WP);
    for (int p = tid; p < HP * WP; p += 256) sP[p] = Pb[p];
    __syncthreads();

    for (int i = tid; i < 49 * LVEC; i += 256) {
        int l = i / 49, k = i - l * 49;
        int ky = k / 7, kx = k - ky * 7;
        int oy = l / OW, ox = l - oy * OW;
        float v = bf2f(sP[(ky + 3 * oy) * WP + (kx + 3 * ox)]);
        float g = 0.5f * v * (1.0f + erff(v * 0.70710678118654752f));  // exact gelu
        hg[(size_t)(n0 + l) * HIDP + c0 + k] = f2bf(g);
    }
}

// ---------------- launch ----------------
extern "C" void kernel_launch(void* const* d_in, const int* in_sizes, int n_in,
                              void* d_out, int out_size, void* d_ws, size_t ws_size,
                              hipStream_t stream) {
    (void)in_sizes; (void)n_in; (void)out_size; (void)ws_size;
    const float* x  = (const float*)d_in[0];
    const float* W1 = (const float*)d_in[1];
    const float* b1 = (const float*)d_in[2];
    const float* W2 = (const float*)d_in[3];
    const float* b2 = (const float*)d_in[4];
    float* out = (float*)d_out;

    char* ws = (char*)d_ws;
    u16* xb  = (u16*)(ws);                                   // 11520*512*2  = 11,796,480
    u16* W1b = (u16*)(ws + 11796480);                        // 2048*512*2   =  2,097,152
    u16* W2b = (u16*)(ws + 11796480 + 2097152);              // 512*2048*2   =  2,097,152
    u16* hg  = (u16*)(ws + 11796480 + 2097152 + 2097152);    // 11520*2048*2 = 47,185,920
    u16* P   = xb;   // xb is dead after GEMM1; P = 640*7524*2 = 9,630,720 B <= 11.8 MB

    // converts
    cvt_x <<<(M_ROWS * DIM) / (256 * 4), 256, 0, stream>>>(x, xb, M_ROWS * DIM);
    cvt_w1<<<(HIDP * DIM) / (256 * 4), 256, 0, stream>>>(W1, W1b);
    cvt_w2<<<(DIM * HIDP) / (256 * 4), 256, 0, stream>>>(W2, W2b);

    // GEMM1: h = x @ W1^T + b1  -> bf16 (11520 x 2048, cols >=1960 are zero)
    gemm_bt<1, 128><<<(M_ROWS / 128) * (HIDP / 128), 256, 0, stream>>>(
        xb, W1b, b1, HID, (void*)hg, HIDP, DIM);

    // middle: fold/normalize -> P (overlaid on xb), then unfold/gelu in place
    midA_fold<<<BPRIME * NCH * 2, 256, 0, stream>>>(hg, P);
    midB_unfold<<<BPRIME * NCH, 256, 0, stream>>>(P, hg);

    // GEMM2: out = g @ W2^T + b2 -> fp32 (11520 x 512), 128x64 tiles for 720 blocks
    gemm_bt<0, 64><<<(M_ROWS / 128) * (DIM / 64), 256, 0, stream>>>(
        hg, W2b, b2, DIM, (void*)out, DIM, HIDP);
}

// Round 4
// 251.440 us; speedup vs baseline: 1.6015x; 1.1028x over previous
//
#include <hip/hip_runtime.h>
#include <cmath>

// ---------------- problem constants ----------------
#define M_ROWS   11520      // 2*5760
#define DIM      512
#define HID      1960
#define HIDP     2048       // padded HID (zeros)
#define KP2      1984       // GEMM2 K-loop bound: 31*64 >= HID, cols [1960,1984) are zero
#define OH       20
#define OW       36
#define LVEC     720        // OH*OW
#define NCH      40         // HID/49
#define BPRIME   16         // M_ROWS / LVEC
#define HP       66         // 60 + 2*3
#define WP       114        // 108 + 2*3

typedef unsigned short u16;
typedef __bf16 bf16x8 __attribute__((ext_vector_type(8)));
typedef float  f32x4  __attribute__((ext_vector_type(4)));

__device__ __forceinline__ u16 f2bf(float f) {
    unsigned u = __float_as_uint(f);
    u += 0x7fffu + ((u >> 16) & 1u);   // RNE
    return (u16)(u >> 16);
}
__device__ __forceinline__ float bf2f(u16 h) {
    return __uint_as_float(((unsigned)h) << 16);
}

__device__ __forceinline__ void gload_lds16(const void* g, void* l) {
    __builtin_amdgcn_global_load_lds(
        (const __attribute__((address_space(1))) void*)g,
        (__attribute__((address_space(3))) void*)l, 16, 0, 0);
}

// ---------------- fp32 -> bf16 converts ----------------
__global__ __launch_bounds__(256) void cvt_x(const float* __restrict__ src,
                                             u16* __restrict__ dst, int n) {
    int i = (blockIdx.x * 256 + threadIdx.x) * 4;
    if (i < n) {
        float4 v = *(const float4*)(src + i);
        ushort4 o;
        o.x = f2bf(v.x); o.y = f2bf(v.y); o.z = f2bf(v.z); o.w = f2bf(v.w);
        *(ushort4*)(dst + i) = o;
    }
}

// W1: (1960,512) -> (2048,512), pad rows with zero
__global__ __launch_bounds__(256) void cvt_w1(const float* __restrict__ src,
                                              u16* __restrict__ dst) {
    int i = (blockIdx.x * 256 + threadIdx.x) * 4;   // over 2048*512
    ushort4 o;
    if (i < HID * DIM) {
        float4 v = *(const float4*)(src + i);
        o.x = f2bf(v.x); o.y = f2bf(v.y); o.z = f2bf(v.z); o.w = f2bf(v.w);
    } else {
        o.x = o.y = o.z = o.w = 0;
    }
    *(ushort4*)(dst + i) = o;
}

// W2: (512,1960) -> (512,2048), pad cols with zero. 1960 % 4 == 0.
__global__ __launch_bounds__(256) void cvt_w2(const float* __restrict__ src,
                                              u16* __restrict__ dst) {
    int i = (blockIdx.x * 256 + threadIdx.x) * 4;   // over 512*2048
    int d = i / HIDP, c = i % HIDP;
    ushort4 o;
    if (c < HID) {
        float4 v = *(const float4*)(src + d * HID + c);
        o.x = f2bf(v.x); o.y = f2bf(v.y); o.z = f2bf(v.z); o.w = f2bf(v.w);
    } else {
        o.x = o.y = o.z = o.w = 0;
    }
    *(ushort4*)(dst + i) = o;
}

// ---------------- bf16 NT-GEMM: C[m,n] = sum_k A[m,k]*B[n,k] + bias[n] ----------------
// 128(M) x BN(N) tile, BK=64, 4 waves (2x2), each wave 64 x BN/2 via
// mfma_f32_16x16x32_bf16. LDS staged with global_load_lds width 16; XOR swizzle
// applied on the GLOBAL side (LDS dest is wave-uniform+lane*16) so ds_read_b128
// is bank-conflict-free.
//
// XCD-locality block swizzle: hardware assigns XCD = blockIdx % 8 (round-robin).
// v = (blockIdx&7)*(NB/8) + (blockIdx>>3) gives each XCD a contiguous strip of
// bm values x all bn -> A-panels are fetched into ONE per-XCD L2 (not 8), and
// the B matrix (2 MB) stays L2-resident. Requires gridDim.x % 8 == 0.
template <int OUT_BF16, int BN>
__global__ __launch_bounds__(256) void gemm_bt(const u16* __restrict__ A,
                                               const u16* __restrict__ B,
                                               const float* __restrict__ bias,
                                               int biasN, void* __restrict__ Cout,
                                               int N, int K, int ldk) {
    constexpr int WN = BN / 2;     // wave N extent
    constexpr int NU = WN / 16;    // acc tiles along N

    __shared__ u16 sA[128 * 64];
    __shared__ u16 sB[BN * 64];

    const int tid  = threadIdx.x;
    const int ntn  = N / BN;
    const int NB   = gridDim.x;
    const int v    = (blockIdx.x & 7) * (NB >> 3) + (blockIdx.x >> 3);
    const int bm   = v / ntn;
    const int bn   = v - bm * ntn;
    const int lane = tid & 63;
    const int wv   = tid >> 6;
    const int wm   = (wv >> 1) * 64;
    const int wn   = (wv & 1) * WN;
    const int r    = lane & 15;
    const int quad = lane >> 4;

    const size_t Arow0 = (size_t)bm * 128 * ldk;
    const size_t Brow0 = (size_t)bn * BN * ldk;

    f32x4 acc[4][NU] = {};

    for (int kt = 0; kt < K; kt += 64) {
        __syncthreads();
#pragma unroll
        for (int i = 0; i < 4; i++) {
            int e   = i * 256 + tid;       // 16B chunk id within A tile
            int row = e >> 3;              // 8 chunks per 128B row
            int cp  = e & 7;
            int cg  = cp ^ (row & 7);      // global chunk fetched into LDS slot cp
            gload_lds16(A + Arow0 + (size_t)row * ldk + kt + cg * 8, (char*)sA + e * 16);
        }
#pragma unroll
        for (int i = 0; i < (BN * 8) / 256; i++) {
            int e   = i * 256 + tid;
            int row = e >> 3;
            int cp  = e & 7;
            int cg  = cp ^ (row & 7);
            gload_lds16(B + Brow0 + (size_t)row * ldk + kt + cg * 8, (char*)sB + e * 16);
        }
        __syncthreads();
#pragma unroll
        for (int kk = 0; kk < 2; kk++) {
            bf16x8 af[4], bg[NU];
#pragma unroll
            for (int t = 0; t < 4; t++) {
                int row = wm + t * 16 + r;
                int c   = (kk * 4 + quad) ^ (row & 7);
                af[t] = *(const bf16x8*)(sA + row * 64 + c * 8);
            }
#pragma unroll
            for (int u = 0; u < NU; u++) {
                int row = wn + u * 16 + r;
                int c   = (kk * 4 + quad) ^ (row & 7);
                bg[u] = *(const bf16x8*)(sB + row * 64 + c * 8);
            }
#pragma unroll
            for (int t = 0; t < 4; t++)
#pragma unroll
                for (int u = 0; u < NU; u++)
                    acc[t][u] = __builtin_amdgcn_mfma_f32_16x16x32_bf16(
                        af[t], bg[u], acc[t][u], 0, 0, 0);
        }
    }

    // epilogue: C/D layout col = lane&15 (n), row = quad*4+q (m)
    const int gm0 = bm * 128 + wm;
    const int gn0 = bn * BN + wn;
#pragma unroll
    for (int u = 0; u < NU; u++) {
        int gn = gn0 + u * 16 + r;
        float bv = (gn < biasN) ? bias[gn] : 0.0f;
#pragma unroll
        for (int t = 0; t < 4; t++) {
            int gm = gm0 + t * 16 + quad * 4;
#pragma unroll
            for (int q = 0; q < 4; q++) {
                float v2 = acc[t][u][q] + bv;
                if (OUT_BF16)
                    ((u16*)Cout)[(size_t)(gm + q) * N + gn] = f2bf(v2);
                else
                    ((float*)Cout)[(size_t)(gm + q) * N + gn] = v2;
            }
        }
    }
}

// ---------------- midA: fold + normalize + crop -> P (bf16 padded image) ----------------
// One block per (b', ch, half). Loads 12 oy-rows of h (coalesced, independent) into
// LDS, then gathers <=9 LDS values per padded pixel (no atomics), normalizes,
// crops borders to zero, writes P rows [3*o0, 3*o0+33]. Halves overlap on P rows
// 30..33 with bit-identical values (same summation order) -> benign double write.
__global__ __launch_bounds__(256) void midA_fold(const u16* __restrict__ hg,
                                                 u16* __restrict__ P) {
    __shared__ u16 sh[12 * OW * 49];   // 21168 u16 = 42336 B

    const int b  = blockIdx.x;
    const int bp = b / (NCH * 2);
    const int rr = b - bp * (NCH * 2);
    const int ch = rr >> 1;
    const int s  = rr & 1;
    const int o0 = s * 10;             // first owned oy
    const int lo = s * 8;              // first loaded oy (0 or 8)
    const int n0 = bp * LVEC;
    const int c0 = ch * 49;
    const int tid = threadIdx.x;

    // phase 0: coalesced load of 12 token-rows x 49 channels
    for (int i = tid; i < 12 * OW * 49; i += 256) {
        int l = i / 49, k = i - l * 49;
        sh[i] = hg[(size_t)(n0 + lo * OW + l) * HIDP + c0 + k];
    }
    __syncthreads();

    // phase 1: gather-fold 34 pixel rows [3*o0 .. 3*o0+33]
    u16* Pb = P + (size_t)(bp * NCH + ch) * (HP * WP) + 3 * o0 * WP;
    for (int p = tid; p < 34 * WP; p += 256) {
        int pyr = p / WP;
        int px  = p - pyr * WP;
        int py  = pyr + 3 * o0;        // absolute padded row
        float val = 0.0f;
        if (py >= 3 && py <= 62 && px >= 3 && px <= 110) {
            int ky0 = py % 3, kx0 = px % 3;
            int cy = 0, cx = 0;
            float sum = 0.0f;
#pragma unroll
            for (int dy = 0; dy < 3; dy++) {
                int ky = ky0 + 3 * dy, ry = py - ky;
                if (ky <= 6 && ry >= 0 && ry <= 57) cy++;
            }
#pragma unroll
            for (int dx = 0; dx < 3; dx++) {
                int kx = kx0 + 3 * dx, rx = px - kx;
                if (kx <= 6 && rx >= 0 && rx <= 105) cx++;
            }
#pragma unroll
            for (int dy = 0; dy < 3; dy++) {
                int ky = ky0 + 3 * dy, ry = py - ky;
                bool vy = (ky <= 6 && ry >= 0 && ry <= 57);
                int lrow = ry / 3 - lo;
#pragma unroll
                for (int dx = 0; dx < 3; dx++) {
                    int kx = kx0 + 3 * dx, rx = px - kx;
                    if (vy && kx <= 6 && rx >= 0 && rx <= 105) {
                        int ox = rx / 3;
                        sum += bf2f(sh[(lrow * OW + ox) * 49 + ky * 7 + kx]);
                    }
                }
            }
            val = sum / (float)(cy * cx);
        }
        Pb[p] = f2bf(val);
    }
}

// ---------------- midB: unfold + gelu, in place over hg ----------------
// One block per (b', ch). Reads only P (no hg reads) -> in-place write is safe.
__global__ __launch_bounds__(256) void midB_unfold(const u16* __restrict__ P,
                                                   u16* __restrict__ hg) {
    __shared__ u16 sP[HP * WP];        // 7524 u16 = 15048 B

    const int b  = blockIdx.x;
    const int bp = b / NCH;
    const int ch = b - bp * NCH;
    const int n0 = bp * LVEC;
    const int c0 = ch * 49;
    const int tid = threadIdx.x;

    const u16* Pb = P + (size_t)(bp * NCH + ch) * (HP * WP);
    for (int p = tid; p < HP * WP; p += 256) sP[p] = Pb[p];
    __syncthreads();

    for (int i = tid; i < 49 * LVEC; i += 256) {
        int l = i / 49, k = i - l * 49;
        int ky = k / 7, kx = k - ky * 7;
        int oy = l / OW, ox = l - oy * OW;
        float v = bf2f(sP[(ky + 3 * oy) * WP + (kx + 3 * ox)]);
        float g = 0.5f * v * (1.0f + erff(v * 0.70710678118654752f));  // exact gelu
        hg[(size_t)(n0 + l) * HIDP + c0 + k] = f2bf(g);
    }
}

// ---------------- launch ----------------
extern "C" void kernel_launch(void* const* d_in, const int* in_sizes, int n_in,
                              void* d_out, int out_size, void* d_ws, size_t ws_size,
                              hipStream_t stream) {
    (void)in_sizes; (void)n_in; (void)out_size; (void)ws_size;
    const float* x  = (const float*)d_in[0];
    const float* W1 = (const float*)d_in[1];
    const float* b1 = (const float*)d_in[2];
    const float* W2 = (const float*)d_in[3];
    const float* b2 = (const float*)d_in[4];
    float* out = (float*)d_out;

    char* ws = (char*)d_ws;
    u16* xb  = (u16*)(ws);                                   // 11520*512*2  = 11,796,480
    u16* W1b = (u16*)(ws + 11796480);                        // 2048*512*2   =  2,097,152
    u16* W2b = (u16*)(ws + 11796480 + 2097152);              // 512*2048*2   =  2,097,152
    u16* hg  = (u16*)(ws + 11796480 + 2097152 + 2097152);    // 11520*2048*2 = 47,185,920
    u16* P   = xb;   // xb is dead after GEMM1; P = 640*7524*2 = 9,630,720 B <= 11.8 MB

    // converts
    cvt_x <<<(M_ROWS * DIM) / (256 * 4), 256, 0, stream>>>(x, xb, M_ROWS * DIM);
    cvt_w1<<<(HIDP * DIM) / (256 * 4), 256, 0, stream>>>(W1, W1b);
    cvt_w2<<<(DIM * HIDP) / (256 * 4), 256, 0, stream>>>(W2, W2b);

    // GEMM1: h = x @ W1^T + b1  -> bf16 (11520 x 2048, cols >=1960 are zero)
    gemm_bt<1, 128><<<(M_ROWS / 128) * (HIDP / 128), 256, 0, stream>>>(
        xb, W1b, b1, HID, (void*)hg, HIDP, DIM, DIM);

    // middle: fold/normalize -> P (overlaid on xb), then unfold/gelu in place
    midA_fold<<<BPRIME * NCH * 2, 256, 0, stream>>>(hg, P);
    midB_unfold<<<BPRIME * NCH, 256, 0, stream>>>(P, hg);

    // GEMM2: out = g @ W2^T + b2 -> fp32 (11520 x 512), 128x64 tiles, K-loop
    // trimmed to 1984 (hg cols [1960,2048) are exactly zero).
    gemm_bt<0, 64><<<(M_ROWS / 128) * (DIM / 64), 256, 0, stream>>>(
        hg, W2b, b2, DIM, (void*)out, DIM, KP2, HIDP);
}

// Round 5
// 224.643 us; speedup vs baseline: 1.7925x; 1.1193x over previous
//
#include <hip/hip_runtime.h>
#include <cmath>

// ---------------- problem constants ----------------
#define M_ROWS   11520      // 2*5760
#define DIM      512
#define HID      1960
#define HIDP     2048       // padded HID (zeros)
#define KP2      1984       // GEMM2 K-loop bound: 31*64 >= HID, cols [1960,1984) are zero
#define OH       20
#define OW       36
#define LVEC     720        // OH*OW
#define NCH      40         // HID/49
#define BPRIME   16         // M_ROWS / LVEC
#define HP       66         // 60 + 2*3
#define WP       114        // 108 + 2*3

typedef unsigned short u16;
typedef __bf16 bf16x8 __attribute__((ext_vector_type(8)));
typedef float  f32x4  __attribute__((ext_vector_type(4)));

__device__ __forceinline__ u16 f2bf(float f) {
    unsigned u = __float_as_uint(f);
    u += 0x7fffu + ((u >> 16) & 1u);   // RNE
    return (u16)(u >> 16);
}
__device__ __forceinline__ float bf2f(u16 h) {
    return __uint_as_float(((unsigned)h) << 16);
}

__device__ __forceinline__ void gload_lds16(const void* g, void* l) {
    __builtin_amdgcn_global_load_lds(
        (const __attribute__((address_space(1))) void*)g,
        (__attribute__((address_space(3))) void*)l, 16, 0, 0);
}

// ---------------- fp32 -> bf16 converts ----------------
__global__ __launch_bounds__(256) void cvt_x(const float* __restrict__ src,
                                             u16* __restrict__ dst, int n) {
    int i = (blockIdx.x * 256 + threadIdx.x) * 4;
    if (i < n) {
        float4 v = *(const float4*)(src + i);
        ushort4 o;
        o.x = f2bf(v.x); o.y = f2bf(v.y); o.z = f2bf(v.z); o.w = f2bf(v.w);
        *(ushort4*)(dst + i) = o;
    }
}

// W1: (1960,512) -> (2048,512), pad rows with zero
__global__ __launch_bounds__(256) void cvt_w1(const float* __restrict__ src,
                                              u16* __restrict__ dst) {
    int i = (blockIdx.x * 256 + threadIdx.x) * 4;   // over 2048*512
    ushort4 o;
    if (i < HID * DIM) {
        float4 v = *(const float4*)(src + i);
        o.x = f2bf(v.x); o.y = f2bf(v.y); o.z = f2bf(v.z); o.w = f2bf(v.w);
    } else {
        o.x = o.y = o.z = o.w = 0;
    }
    *(ushort4*)(dst + i) = o;
}

// W2: (512,1960) -> (512,2048), pad cols with zero. 1960 % 4 == 0.
__global__ __launch_bounds__(256) void cvt_w2(const float* __restrict__ src,
                                              u16* __restrict__ dst) {
    int i = (blockIdx.x * 256 + threadIdx.x) * 4;   // over 512*2048
    int d = i / HIDP, c = i % HIDP;
    ushort4 o;
    if (c < HID) {
        float4 v = *(const float4*)(src + d * HID + c);
        o.x = f2bf(v.x); o.y = f2bf(v.y); o.z = f2bf(v.z); o.w = f2bf(v.w);
    } else {
        o.x = o.y = o.z = o.w = 0;
    }
    *(ushort4*)(dst + i) = o;
}

// ---------------- bf16 NT-GEMM: C[m,n] = sum_k A[m,k]*B[n,k] + bias[n] ----------------
// 128(M) x BN(N) tile, BK=64, 4 waves (2x2), each wave 64 x BN/2 via
// mfma_f32_16x16x32_bf16. LDS staged with global_load_lds width 16; XOR swizzle
// applied on the GLOBAL side (LDS dest is wave-uniform+lane*16) so ds_read_b128
// is bank-conflict-free.
//
// XCD-locality block swizzle: hardware assigns XCD = blockIdx % 8 (round-robin).
// v = (blockIdx&7)*(NB/8) + (blockIdx>>3) gives each XCD a contiguous strip of
// bm values x all bn -> A-panels are fetched into ONE per-XCD L2 (not 8), and
// the B matrix (2 MB) stays L2-resident. Requires gridDim.x % 8 == 0.
template <int OUT_BF16, int BN>
__global__ __launch_bounds__(256) void gemm_bt(const u16* __restrict__ A,
                                               const u16* __restrict__ B,
                                               const float* __restrict__ bias,
                                               int biasN, void* __restrict__ Cout,
                                               int N, int K, int ldk) {
    constexpr int WN = BN / 2;     // wave N extent
    constexpr int NU = WN / 16;    // acc tiles along N

    __shared__ u16 sA[128 * 64];
    __shared__ u16 sB[BN * 64];

    const int tid  = threadIdx.x;
    const int ntn  = N / BN;
    const int NB   = gridDim.x;
    const int v    = (blockIdx.x & 7) * (NB >> 3) + (blockIdx.x >> 3);
    const int bm   = v / ntn;
    const int bn   = v - bm * ntn;
    const int lane = tid & 63;
    const int wv   = tid >> 6;
    const int wm   = (wv >> 1) * 64;
    const int wn   = (wv & 1) * WN;
    const int r    = lane & 15;
    const int quad = lane >> 4;

    const size_t Arow0 = (size_t)bm * 128 * ldk;
    const size_t Brow0 = (size_t)bn * BN * ldk;

    f32x4 acc[4][NU] = {};

    for (int kt = 0; kt < K; kt += 64) {
        __syncthreads();
#pragma unroll
        for (int i = 0; i < 4; i++) {
            int e   = i * 256 + tid;       // 16B chunk id within A tile
            int row = e >> 3;              // 8 chunks per 128B row
            int cp  = e & 7;
            int cg  = cp ^ (row & 7);      // global chunk fetched into LDS slot cp
            gload_lds16(A + Arow0 + (size_t)row * ldk + kt + cg * 8, (char*)sA + e * 16);
        }
#pragma unroll
        for (int i = 0; i < (BN * 8) / 256; i++) {
            int e   = i * 256 + tid;
            int row = e >> 3;
            int cp  = e & 7;
            int cg  = cp ^ (row & 7);
            gload_lds16(B + Brow0 + (size_t)row * ldk + kt + cg * 8, (char*)sB + e * 16);
        }
        __syncthreads();
#pragma unroll
        for (int kk = 0; kk < 2; kk++) {
            bf16x8 af[4], bg[NU];
#pragma unroll
            for (int t = 0; t < 4; t++) {
                int row = wm + t * 16 + r;
                int c   = (kk * 4 + quad) ^ (row & 7);
                af[t] = *(const bf16x8*)(sA + row * 64 + c * 8);
            }
#pragma unroll
            for (int u = 0; u < NU; u++) {
                int row = wn + u * 16 + r;
                int c   = (kk * 4 + quad) ^ (row & 7);
                bg[u] = *(const bf16x8*)(sB + row * 64 + c * 8);
            }
#pragma unroll
            for (int t = 0; t < 4; t++)
#pragma unroll
                for (int u = 0; u < NU; u++)
                    acc[t][u] = __builtin_amdgcn_mfma_f32_16x16x32_bf16(
                        af[t], bg[u], acc[t][u], 0, 0, 0);
        }
    }

    // epilogue: C/D layout col = lane&15 (n), row = quad*4+q (m)
    const int gm0 = bm * 128 + wm;
    const int gn0 = bn * BN + wn;
#pragma unroll
    for (int u = 0; u < NU; u++) {
        int gn = gn0 + u * 16 + r;
        float bv = (gn < biasN) ? bias[gn] : 0.0f;
#pragma unroll
        for (int t = 0; t < 4; t++) {
            int gm = gm0 + t * 16 + quad * 4;
#pragma unroll
            for (int q = 0; q < 4; q++) {
                float v2 = acc[t][u][q] + bv;
                if (OUT_BF16)
                    ((u16*)Cout)[(size_t)(gm + q) * N + gn] = f2bf(v2);
                else
                    ((float*)Cout)[(size_t)(gm + q) * N + gn] = v2;
            }
        }
    }
}

// ---------------- midA: fold + normalize + crop + GELU -> G (bf16 padded image) ----------------
// One block per (b', ch, half). Loads 12 oy-rows of h (coalesced, independent) into
// LDS, then gathers <=9 LDS values per padded pixel (no atomics), normalizes,
// crops borders to zero, applies exact gelu ONCE PER PIXEL (gelu commutes with the
// unfold gather), writes G rows [3*o0, 3*o0+33]. Halves overlap on rows 30..33
// with bit-identical values -> benign double write.
__global__ __launch_bounds__(256) void midA_fold(const u16* __restrict__ hg,
                                                 u16* __restrict__ G) {
    __shared__ u16 sh[12 * OW * 49];   // 21168 u16 = 42336 B

    const int b  = blockIdx.x;
    const int bp = b / (NCH * 2);
    const int rr = b - bp * (NCH * 2);
    const int ch = rr >> 1;
    const int s  = rr & 1;
    const int o0 = s * 10;             // first owned oy
    const int lo = s * 8;              // first loaded oy (0 or 8)
    const int n0 = bp * LVEC;
    const int c0 = ch * 49;
    const int tid = threadIdx.x;

    // phase 0: coalesced load of 12 token-rows x 49 channels
    for (int i = tid; i < 12 * OW * 49; i += 256) {
        int l = i / 49, k = i - l * 49;
        sh[i] = hg[(size_t)(n0 + lo * OW + l) * HIDP + c0 + k];
    }
    __syncthreads();

    // phase 1: gather-fold 34 pixel rows [3*o0 .. 3*o0+33], then gelu
    u16* Gb = G + (size_t)(bp * NCH + ch) * (HP * WP) + 3 * o0 * WP;
    for (int p = tid; p < 34 * WP; p += 256) {
        int pyr = p / WP;
        int px  = p - pyr * WP;
        int py  = pyr + 3 * o0;        // absolute padded row
        float val = 0.0f;
        if (py >= 3 && py <= 62 && px >= 3 && px <= 110) {
            int ky0 = py % 3, kx0 = px % 3;
            int cy = 0, cx = 0;
            float sum = 0.0f;
#pragma unroll
            for (int dy = 0; dy < 3; dy++) {
                int ky = ky0 + 3 * dy, ry = py - ky;
                if (ky <= 6 && ry >= 0 && ry <= 57) cy++;
            }
#pragma unroll
            for (int dx = 0; dx < 3; dx++) {
                int kx = kx0 + 3 * dx, rx = px - kx;
                if (kx <= 6 && rx >= 0 && rx <= 105) cx++;
            }
#pragma unroll
            for (int dy = 0; dy < 3; dy++) {
                int ky = ky0 + 3 * dy, ry = py - ky;
                bool vy = (ky <= 6 && ry >= 0 && ry <= 57);
                int lrow = ry / 3 - lo;
#pragma unroll
                for (int dx = 0; dx < 3; dx++) {
                    int kx = kx0 + 3 * dx, rx = px - kx;
                    if (vy && kx <= 6 && rx >= 0 && rx <= 105) {
                        int ox = rx / 3;
                        sum += bf2f(sh[(lrow * OW + ox) * 49 + ky * 7 + kx]);
                    }
                }
            }
            float m = sum / (float)(cy * cx);
            val = 0.5f * m * (1.0f + erff(m * 0.70710678118654752f));  // exact gelu
        }
        Gb[p] = f2bf(val);
    }
}

// ---------------- midB: unfold (pure u16 gather), in place over hg ----------------
// One block per (b', ch, half). Reads only G (no hg reads) -> in-place write is
// safe. No float math: bf16 values copied through LDS verbatim.
__global__ __launch_bounds__(256) void midB_unfold(const u16* __restrict__ G,
                                                   u16* __restrict__ hg) {
    __shared__ u16 sG[34 * WP];        // 3876 u16 = 7752 B

    const int b  = blockIdx.x;
    const int bp = b / (NCH * 2);
    const int rr = b - bp * (NCH * 2);
    const int ch = rr >> 1;
    const int s  = rr & 1;
    const int o0 = s * 10;             // first owned oy
    const int n0 = bp * LVEC + o0 * OW;
    const int c0 = ch * 49;
    const int tid = threadIdx.x;

    const u16* Gb = G + (size_t)(bp * NCH + ch) * (HP * WP) + 3 * o0 * WP;
    for (int p = tid; p < 34 * WP; p += 256) sG[p] = Gb[p];
    __syncthreads();

    for (int i = tid; i < 10 * OW * 49; i += 256) {
        int l = i / 49, k = i - l * 49;     // l in [0,360)
        int ky = k / 7, kx = k - ky * 7;
        int oy = l / OW, ox = l - oy * OW;  // oy in [0,10)
        hg[(size_t)(n0 + l) * HIDP + c0 + k] = sG[(3 * oy + ky) * WP + kx + 3 * ox];
    }
}

// ---------------- launch ----------------
extern "C" void kernel_launch(void* const* d_in, const int* in_sizes, int n_in,
                              void* d_out, int out_size, void* d_ws, size_t ws_size,
                              hipStream_t stream) {
    (void)in_sizes; (void)n_in; (void)out_size; (void)ws_size;
    const float* x  = (const float*)d_in[0];
    const float* W1 = (const float*)d_in[1];
    const float* b1 = (const float*)d_in[2];
    const float* W2 = (const float*)d_in[3];
    const float* b2 = (const float*)d_in[4];
    float* out = (float*)d_out;

    char* ws = (char*)d_ws;
    u16* xb  = (u16*)(ws);                                   // 11520*512*2  = 11,796,480
    u16* W1b = (u16*)(ws + 11796480);                        // 2048*512*2   =  2,097,152
    u16* W2b = (u16*)(ws + 11796480 + 2097152);              // 512*2048*2   =  2,097,152
    u16* hg  = (u16*)(ws + 11796480 + 2097152 + 2097152);    // 11520*2048*2 = 47,185,920
    u16* G   = xb;   // xb is dead after GEMM1; G = 640*7524*2 = 9,630,720 B <= 11.8 MB

    // converts
    cvt_x <<<(M_ROWS * DIM) / (256 * 4), 256, 0, stream>>>(x, xb, M_ROWS * DIM);
    cvt_w1<<<(HIDP * DIM) / (256 * 4), 256, 0, stream>>>(W1, W1b);
    cvt_w2<<<(DIM * HIDP) / (256 * 4), 256, 0, stream>>>(W2, W2b);

    // GEMM1: h = x @ W1^T + b1  -> bf16 (11520 x 2048, cols >=1960 are zero)
    gemm_bt<1, 128><<<(M_ROWS / 128) * (HIDP / 128), 256, 0, stream>>>(
        xb, W1b, b1, HID, (void*)hg, HIDP, DIM, DIM);

    // middle: fold/normalize/gelu -> G (overlaid on xb), then unfold in place
    midA_fold<<<BPRIME * NCH * 2, 256, 0, stream>>>(hg, G);
    midB_unfold<<<BPRIME * NCH * 2, 256, 0, stream>>>(G, hg);

    // GEMM2: out = g @ W2^T + b2 -> fp32 (11520 x 512), 128x64 tiles, K-loop
    // trimmed to 1984 (hg cols [1960,2048) are exactly zero).
    gemm_bt<0, 64><<<(M_ROWS / 128) * (DIM / 64), 256, 0, stream>>>(
        hg, W2b, b2, DIM, (void*)out, DIM, KP2, HIDP);
}

// Round 6
// 209.452 us; speedup vs baseline: 1.9225x; 1.0725x over previous
//
#include <hip/hip_runtime.h>
#include <cmath>

// ---------------- problem constants ----------------
#define M_ROWS   11520      // 2*5760
#define DIM      512
#define HID      1960
#define HIDP     2048       // padded HID (zeros)
#define KP2      1984       // GEMM2 K-loop bound: 31*64 >= HID, cols [1960,1984) are zero
#define OH       20
#define OW       36
#define LVEC     720        // OH*OW
#define NCH      40         // HID/49
#define BPRIME   16         // M_ROWS / LVEC
#define HP       66         // 60 + 2*3
#define WP       114        // 108 + 2*3

typedef unsigned short u16;
typedef __bf16 bf16x8 __attribute__((ext_vector_type(8)));
typedef float  f32x4  __attribute__((ext_vector_type(4)));

__device__ __forceinline__ u16 f2bf(float f) {
    unsigned u = __float_as_uint(f);
    u += 0x7fffu + ((u >> 16) & 1u);   // RNE
    return (u16)(u >> 16);
}
__device__ __forceinline__ float bf2f(u16 h) {
    return __uint_as_float(((unsigned)h) << 16);
}

__device__ __forceinline__ void gload_lds16(const void* g, void* l) {
    __builtin_amdgcn_global_load_lds(
        (const __attribute__((address_space(1))) void*)g,
        (__attribute__((address_space(3))) void*)l, 16, 0, 0);
}

// ---------------- fp32 -> bf16 converts ----------------
__global__ __launch_bounds__(256) void cvt_x(const float* __restrict__ src,
                                             u16* __restrict__ dst, int n) {
    int i = (blockIdx.x * 256 + threadIdx.x) * 4;
    if (i < n) {
        float4 v = *(const float4*)(src + i);
        ushort4 o;
        o.x = f2bf(v.x); o.y = f2bf(v.y); o.z = f2bf(v.z); o.w = f2bf(v.w);
        *(ushort4*)(dst + i) = o;
    }
}

// W1: (1960,512) -> (2048,512), pad rows with zero
__global__ __launch_bounds__(256) void cvt_w1(const float* __restrict__ src,
                                              u16* __restrict__ dst) {
    int i = (blockIdx.x * 256 + threadIdx.x) * 4;   // over 2048*512
    ushort4 o;
    if (i < HID * DIM) {
        float4 v = *(const float4*)(src + i);
        o.x = f2bf(v.x); o.y = f2bf(v.y); o.z = f2bf(v.z); o.w = f2bf(v.w);
    } else {
        o.x = o.y = o.z = o.w = 0;
    }
    *(ushort4*)(dst + i) = o;
}

// W2: (512,1960) -> (512,2048), pad cols with zero. 1960 % 4 == 0.
__global__ __launch_bounds__(256) void cvt_w2(const float* __restrict__ src,
                                              u16* __restrict__ dst) {
    int i = (blockIdx.x * 256 + threadIdx.x) * 4;   // over 512*2048
    int d = i / HIDP, c = i % HIDP;
    ushort4 o;
    if (c < HID) {
        float4 v = *(const float4*)(src + d * HID + c);
        o.x = f2bf(v.x); o.y = f2bf(v.y); o.z = f2bf(v.z); o.w = f2bf(v.w);
    } else {
        o.x = o.y = o.z = o.w = 0;
    }
    *(ushort4*)(dst + i) = o;
}

// ---------------- bf16 NT-GEMM: C[m,n] = sum_k A[m,k]*B[n,k] + bias[n] ----------------
// 128(M) x BN(N) tile, BK=64, 4 waves (2x2), each wave 64 x BN/2 via
// mfma_f32_16x16x32_bf16. LDS staged with global_load_lds width 16; XOR swizzle
// applied on the GLOBAL side (LDS dest is wave-uniform+lane*16) so ds_read_b128
// is bank-conflict-free.
//
// XCD-locality block swizzle: hardware assigns XCD = blockIdx % 8 (round-robin).
// v = (blockIdx&7)*(NB/8) + (blockIdx>>3) gives each XCD a contiguous strip of
// bm values x all bn -> A-panels are fetched into ONE per-XCD L2 (not 8), and
// the B matrix (2 MB) stays L2-resident. Requires gridDim.x % 8 == 0.
template <int OUT_BF16, int BN>
__global__ __launch_bounds__(256) void gemm_bt(const u16* __restrict__ A,
                                               const u16* __restrict__ B,
                                               const float* __restrict__ bias,
                                               int biasN, void* __restrict__ Cout,
                                               int N, int K, int ldk) {
    constexpr int WN = BN / 2;     // wave N extent
    constexpr int NU = WN / 16;    // acc tiles along N

    __shared__ u16 sA[128 * 64];
    __shared__ u16 sB[BN * 64];

    const int tid  = threadIdx.x;
    const int ntn  = N / BN;
    const int NB   = gridDim.x;
    const int v    = (blockIdx.x & 7) * (NB >> 3) + (blockIdx.x >> 3);
    const int bm   = v / ntn;
    const int bn   = v - bm * ntn;
    const int lane = tid & 63;
    const int wv   = tid >> 6;
    const int wm   = (wv >> 1) * 64;
    const int wn   = (wv & 1) * WN;
    const int r    = lane & 15;
    const int quad = lane >> 4;

    const size_t Arow0 = (size_t)bm * 128 * ldk;
    const size_t Brow0 = (size_t)bn * BN * ldk;

    f32x4 acc[4][NU] = {};

    for (int kt = 0; kt < K; kt += 64) {
        __syncthreads();
#pragma unroll
        for (int i = 0; i < 4; i++) {
            int e   = i * 256 + tid;       // 16B chunk id within A tile
            int row = e >> 3;              // 8 chunks per 128B row
            int cp  = e & 7;
            int cg  = cp ^ (row & 7);      // global chunk fetched into LDS slot cp
            gload_lds16(A + Arow0 + (size_t)row * ldk + kt + cg * 8, (char*)sA + e * 16);
        }
#pragma unroll
        for (int i = 0; i < (BN * 8) / 256; i++) {
            int e   = i * 256 + tid;
            int row = e >> 3;
            int cp  = e & 7;
            int cg  = cp ^ (row & 7);
            gload_lds16(B + Brow0 + (size_t)row * ldk + kt + cg * 8, (char*)sB + e * 16);
        }
        __syncthreads();
#pragma unroll
        for (int kk = 0; kk < 2; kk++) {
            bf16x8 af[4], bg[NU];
#pragma unroll
            for (int t = 0; t < 4; t++) {
                int row = wm + t * 16 + r;
                int c   = (kk * 4 + quad) ^ (row & 7);
                af[t] = *(const bf16x8*)(sA + row * 64 + c * 8);
            }
#pragma unroll
            for (int u = 0; u < NU; u++) {
                int row = wn + u * 16 + r;
                int c   = (kk * 4 + quad) ^ (row & 7);
                bg[u] = *(const bf16x8*)(sB + row * 64 + c * 8);
            }
#pragma unroll
            for (int t = 0; t < 4; t++)
#pragma unroll
                for (int u = 0; u < NU; u++)
                    acc[t][u] = __builtin_amdgcn_mfma_f32_16x16x32_bf16(
                        af[t], bg[u], acc[t][u], 0, 0, 0);
        }
    }

    // epilogue: C/D layout col = lane&15 (n), row = quad*4+q (m)
    const int gm0 = bm * 128 + wm;
    const int gn0 = bn * BN + wn;
#pragma unroll
    for (int u = 0; u < NU; u++) {
        int gn = gn0 + u * 16 + r;
        float bv = (gn < biasN) ? bias[gn] : 0.0f;
#pragma unroll
        for (int t = 0; t < 4; t++) {
            int gm = gm0 + t * 16 + quad * 4;
#pragma unroll
            for (int q = 0; q < 4; q++) {
                float v2 = acc[t][u][q] + bv;
                if (OUT_BF16)
                    ((u16*)Cout)[(size_t)(gm + q) * N + gn] = f2bf(v2);
                else
                    ((float*)Cout)[(size_t)(gm + q) * N + gn] = v2;
            }
        }
    }
}

// ---------------- midA: fold + normalize + crop + GELU -> G (bf16 padded image) ----------------
// One block per (b', ch, quarter). Quarter s owns pixel rows [15s, 15s+15)
// (s=3: [45,66)) -- disjoint, all 66 rows covered. Loads the <=7 oy-rows that
// feed those pixel rows into LDS (coalesced), then column-strip threading:
// thread = (px = tid&127, row-parity = tid>>7). All px-dependent terms
// (kx validity, colterm = ox*49+kx, 1/cx) hoisted out of the row loop; all
// row-dependent terms (ky validity, row term, 1/cy) are wave-uniform (scalar).
// GELU applied once per pixel. No atomics, no divides, no per-gather index math.
__global__ __launch_bounds__(256) void midA_fold(const u16* __restrict__ hg,
                                                 u16* __restrict__ G) {
    __shared__ u16 sh[7 * OW * 49];    // 12348 u16 = 24696 B

    const int b  = blockIdx.x;
    const int bp = b / (NCH * 4);
    const int rr = b - bp * (NCH * 4);
    const int ch = rr >> 2;
    const int s  = rr & 3;
    const int lo    = (s == 0) ? 0 : (5 * s - 2);   // first loaded oy
    const int nload = (s == 0) ? 5 : 7;             // oy-rows loaded
    const int row0  = 15 * s;                       // first owned pixel row
    const int nrows = (s == 3) ? 21 : 15;           // owned pixel rows
    const int n0 = bp * LVEC;
    const int c0 = ch * 49;
    const int tid = threadIdx.x;

    // phase 0: coalesced load of nload token-rows x 49 channels
    for (int i = tid; i < nload * OW * 49; i += 256) {
        int l = i / 49, k = i - l * 49;
        sh[i] = hg[(size_t)(n0 + lo * OW + l) * HIDP + c0 + k];
    }
    __syncthreads();

    const int px = tid & 127;          // column owned by this thread
    const int rg = tid >> 7;           // row parity (wave-uniform)
    if (px >= WP) return;

    // hoisted px-side terms
    const bool pxin = (px >= 3) && (px <= 110);
    const int kx0 = px % 3;
    int  ct[3];
    bool vx[3];
    int  cx = 0;
#pragma unroll
    for (int dx = 0; dx < 3; dx++) {
        int kx = kx0 + 3 * dx, rx = px - kx;
        bool ok = pxin && (kx <= 6) && (rx >= 0) && (rx <= 105);
        vx[dx] = ok;
        ct[dx] = ok ? ((rx / 3) * 49 + kx) : 0;
        cx += ok ? 1 : 0;
    }
    const float fcx = (cx == 3) ? (1.0f / 3.0f) : ((cx == 2) ? 0.5f : 1.0f);

    u16* Gb = G + (size_t)(bp * NCH + ch) * (HP * WP);
    for (int ri = rg; ri < nrows; ri += 2) {
        int py = row0 + ri;            // wave-uniform
        float val = 0.0f;
        if (pxin && py >= 3 && py <= 62) {
            int ky0 = py % 3;
            float sum = 0.0f;
            int cy = 0;
#pragma unroll
            for (int dy = 0; dy < 3; dy++) {
                int ky = ky0 + 3 * dy, ry = py - ky;   // uniform
                if (ky <= 6 && ry >= 0 && ry <= 57) {  // uniform branch
                    int rt = (ry / 3 - lo) * (OW * 49) + ky * 7;
                    cy++;
                    float v0 = bf2f(sh[rt + ct[0]]);
                    float v1 = bf2f(sh[rt + ct[1]]);
                    float v2 = bf2f(sh[rt + ct[2]]);
                    sum += vx[0] ? v0 : 0.0f;
                    sum += vx[1] ? v1 : 0.0f;
                    sum += vx[2] ? v2 : 0.0f;
                }
            }
            float fcy = (cy == 3) ? (1.0f / 3.0f) : ((cy == 2) ? 0.5f : 1.0f);
            float m = sum * fcx * fcy;
            val = 0.5f * m * (1.0f + erff(m * 0.70710678118654752f));  // exact gelu
        }
        Gb[py * WP + px] = f2bf(val);
    }
}

// ---------------- midB: unfold (pure u16 gather), in place over hg ----------------
// One block per (b', ch, half). Reads only G (no hg reads) -> in-place write is
// safe. No float math: bf16 values copied through LDS verbatim.
__global__ __launch_bounds__(256) void midB_unfold(const u16* __restrict__ G,
                                                   u16* __restrict__ hg) {
    __shared__ u16 sG[34 * WP];        // 3876 u16 = 7752 B

    const int b  = blockIdx.x;
    const int bp = b / (NCH * 2);
    const int rr = b - bp * (NCH * 2);
    const int ch = rr >> 1;
    const int s  = rr & 1;
    const int o0 = s * 10;             // first owned oy
    const int n0 = bp * LVEC + o0 * OW;
    const int c0 = ch * 49;
    const int tid = threadIdx.x;

    const u16* Gb = G + (size_t)(bp * NCH + ch) * (HP * WP) + 3 * o0 * WP;
    for (int p = tid; p < 34 * WP; p += 256) sG[p] = Gb[p];
    __syncthreads();

    for (int i = tid; i < 10 * OW * 49; i += 256) {
        int l = i / 49, k = i - l * 49;     // l in [0,360)
        int ky = k / 7, kx = k - ky * 7;
        int oy = l / OW, ox = l - oy * OW;  // oy in [0,10)
        hg[(size_t)(n0 + l) * HIDP + c0 + k] = sG[(3 * oy + ky) * WP + kx + 3 * ox];
    }
}

// ---------------- launch ----------------
extern "C" void kernel_launch(void* const* d_in, const int* in_sizes, int n_in,
                              void* d_out, int out_size, void* d_ws, size_t ws_size,
                              hipStream_t stream) {
    (void)in_sizes; (void)n_in; (void)out_size; (void)ws_size;
    const float* x  = (const float*)d_in[0];
    const float* W1 = (const float*)d_in[1];
    const float* b1 = (const float*)d_in[2];
    const float* W2 = (const float*)d_in[3];
    const float* b2 = (const float*)d_in[4];
    float* out = (float*)d_out;

    char* ws = (char*)d_ws;
    u16* xb  = (u16*)(ws);                                   // 11520*512*2  = 11,796,480
    u16* W1b = (u16*)(ws + 11796480);                        // 2048*512*2   =  2,097,152
    u16* W2b = (u16*)(ws + 11796480 + 2097152);              // 512*2048*2   =  2,097,152
    u16* hg  = (u16*)(ws + 11796480 + 2097152 + 2097152);    // 11520*2048*2 = 47,185,920
    u16* G   = xb;   // xb is dead after GEMM1; G = 640*7524*2 = 9,630,720 B <= 11.8 MB

    // converts
    cvt_x <<<(M_ROWS * DIM) / (256 * 4), 256, 0, stream>>>(x, xb, M_ROWS * DIM);
    cvt_w1<<<(HIDP * DIM) / (256 * 4), 256, 0, stream>>>(W1, W1b);
    cvt_w2<<<(DIM * HIDP) / (256 * 4), 256, 0, stream>>>(W2, W2b);

    // GEMM1: h = x @ W1^T + b1  -> bf16 (11520 x 2048, cols >=1960 are zero)
    gemm_bt<1, 128><<<(M_ROWS / 128) * (HIDP / 128), 256, 0, stream>>>(
        xb, W1b, b1, HID, (void*)hg, HIDP, DIM, DIM);

    // middle: fold/normalize/gelu -> G (overlaid on xb), then unfold in place
    midA_fold<<<BPRIME * NCH * 4, 256, 0, stream>>>(hg, G);
    midB_unfold<<<BPRIME * NCH * 2, 256, 0, stream>>>(G, hg);

    // GEMM2: out = g @ W2^T + b2 -> fp32 (11520 x 512), 128x64 tiles, K-loop
    // trimmed to 1984 (hg cols [1960,2048) are exactly zero).
    gemm_bt<0, 64><<<(M_ROWS / 128) * (DIM / 64), 256, 0, stream>>>(
        hg, W2b, b2, DIM, (void*)out, DIM, KP2, HIDP);
}

// Round 7
// 204.345 us; speedup vs baseline: 1.9706x; 1.0250x over previous
//
#include <hip/hip_runtime.h>
#include <cmath>

// ---------------- problem constants ----------------
#define M_ROWS   11520      // 2*5760
#define DIM      512
#define HID      1960
#define HIDP     2048       // padded HID (zeros)
#define KP2      1984       // GEMM2 K-loop bound: 31*64 >= HID, cols [1960,1984) are zero
#define OH       20
#define OW       36
#define LVEC     720        // OH*OW
#define NCH      40         // HID/49
#define BPRIME   16         // M_ROWS / LVEC
#define HP       66         // 60 + 2*3
#define WP       114        // 108 + 2*3

typedef unsigned short u16;
typedef __bf16 bf16x8 __attribute__((ext_vector_type(8)));
typedef float  f32x4  __attribute__((ext_vector_type(4)));

__device__ __forceinline__ u16 f2bf(float f) {
    unsigned u = __float_as_uint(f);
    u += 0x7fffu + ((u >> 16) & 1u);   // RNE
    return (u16)(u >> 16);
}
__device__ __forceinline__ float bf2f(u16 h) {
    return __uint_as_float(((unsigned)h) << 16);
}

__device__ __forceinline__ void gload_lds16(const void* g, void* l) {
    __builtin_amdgcn_global_load_lds(
        (const __attribute__((address_space(1))) void*)g,
        (__attribute__((address_space(3))) void*)l, 16, 0, 0);
}

// ---------------- fused fp32 -> bf16 converts (one dispatch) ----------------
// blocks [0, 5760): x (11520x512); [5760, 6784): W1 pad-rows; [6784, 7808): W2 pad-cols
#define CVT_XB   5760
#define CVT_W1B  1024
__global__ __launch_bounds__(256) void cvt_all(const float* __restrict__ x,
                                               const float* __restrict__ W1,
                                               const float* __restrict__ W2,
                                               u16* __restrict__ xb,
                                               u16* __restrict__ W1b,
                                               u16* __restrict__ W2b) {
    const int b = blockIdx.x;
    const int tid = threadIdx.x;
    ushort4 o;
    if (b < CVT_XB) {
        int i = (b * 256 + tid) * 4;
        float4 v = *(const float4*)(x + i);
        o.x = f2bf(v.x); o.y = f2bf(v.y); o.z = f2bf(v.z); o.w = f2bf(v.w);
        *(ushort4*)(xb + i) = o;
    } else if (b < CVT_XB + CVT_W1B) {
        int i = ((b - CVT_XB) * 256 + tid) * 4;      // over 2048*512
        if (i < HID * DIM) {
            float4 v = *(const float4*)(W1 + i);
            o.x = f2bf(v.x); o.y = f2bf(v.y); o.z = f2bf(v.z); o.w = f2bf(v.w);
        } else {
            o.x = o.y = o.z = o.w = 0;
        }
        *(ushort4*)(W1b + i) = o;
    } else {
        int i = ((b - CVT_XB - CVT_W1B) * 256 + tid) * 4;   // over 512*2048
        int d = i / HIDP, c = i - d * HIDP;
        if (c < HID) {
            float4 v = *(const float4*)(W2 + (size_t)d * HID + c);
            o.x = f2bf(v.x); o.y = f2bf(v.y); o.z = f2bf(v.z); o.w = f2bf(v.w);
        } else {
            o.x = o.y = o.z = o.w = 0;
        }
        *(ushort4*)(W2b + i) = o;
    }
}

// ---------------- bf16 NT-GEMM: C[m,n] = sum_k A[m,k]*B[n,k] + bias[n] ----------------
// 128(M) x BN(N) tile, BK=64, 512 threads = 8 waves (4 M x 2 N), each wave
// 32 x BN/2 via mfma_f32_16x16x32_bf16. 8 waves/block doubles resident
// waves/CU vs the 4-wave version (GEMM K-loops here are short and
// barrier/latency-bound: round-3 PMC showed MfmaUtil 15% / VALUBusy 17%).
// LDS staged with global_load_lds width 16; XOR swizzle applied on the GLOBAL
// side (LDS dest is wave-uniform+lane*16) so ds_read_b128 is conflict-free.
//
// XCD-locality block swizzle: hardware assigns XCD = blockIdx % 8 (round-robin).
// v = (blockIdx&7)*(NB/8) + (blockIdx>>3) gives each XCD a contiguous strip of
// bm values x all bn -> A-panels are fetched into ONE per-XCD L2 (not 8), and
// the B matrix (2 MB) stays L2-resident. Requires gridDim.x % 8 == 0.
template <int OUT_BF16, int BN>
__global__ __launch_bounds__(512) void gemm_bt(const u16* __restrict__ A,
                                               const u16* __restrict__ B,
                                               const float* __restrict__ bias,
                                               int biasN, void* __restrict__ Cout,
                                               int N, int K, int ldk) {
    constexpr int WN = BN / 2;       // wave N extent
    constexpr int NU = WN / 16;      // acc tiles along N (4 or 2)
    constexpr int BCH = BN * 8;      // B-tile 16B chunks (1024 or 512)

    __shared__ u16 sA[128 * 64];
    __shared__ u16 sB[BN * 64];

    const int tid  = threadIdx.x;
    const int ntn  = N / BN;
    const int NB   = gridDim.x;
    const int v    = (blockIdx.x & 7) * (NB >> 3) + (blockIdx.x >> 3);
    const int bm   = v / ntn;
    const int bn   = v - bm * ntn;
    const int lane = tid & 63;
    const int wv   = tid >> 6;       // 0..7
    const int wm   = (wv >> 1) * 32; // 4 wave-rows of 32
    const int wn   = (wv & 1) * WN;  // 2 wave-cols
    const int r    = lane & 15;
    const int quad = lane >> 4;

    const size_t Arow0 = (size_t)bm * 128 * ldk;
    const size_t Brow0 = (size_t)bn * BN * ldk;

    f32x4 acc[2][NU] = {};

    for (int kt = 0; kt < K; kt += 64) {
        __syncthreads();
#pragma unroll
        for (int i = 0; i < 2; i++) {          // A: 1024 chunks / 512 threads
            int e   = i * 512 + tid;
            int row = e >> 3;
            int cp  = e & 7;
            int cg  = cp ^ (row & 7);
            gload_lds16(A + Arow0 + (size_t)row * ldk + kt + cg * 8, (char*)sA + e * 16);
        }
#pragma unroll
        for (int i = 0; i < BCH / 512; i++) {  // B: BCH chunks / 512 threads
            int e   = i * 512 + tid;
            int row = e >> 3;
            int cp  = e & 7;
            int cg  = cp ^ (row & 7);
            gload_lds16(B + Brow0 + (size_t)row * ldk + kt + cg * 8, (char*)sB + e * 16);
        }
        __syncthreads();
#pragma unroll
        for (int kk = 0; kk < 2; kk++) {
            bf16x8 af[2], bg[NU];
#pragma unroll
            for (int t = 0; t < 2; t++) {
                int row = wm + t * 16 + r;
                int c   = (kk * 4 + quad) ^ (row & 7);
                af[t] = *(const bf16x8*)(sA + row * 64 + c * 8);
            }
#pragma unroll
            for (int u = 0; u < NU; u++) {
                int row = wn + u * 16 + r;
                int c   = (kk * 4 + quad) ^ (row & 7);
                bg[u] = *(const bf16x8*)(sB + row * 64 + c * 8);
            }
#pragma unroll
            for (int t = 0; t < 2; t++)
#pragma unroll
                for (int u = 0; u < NU; u++)
                    acc[t][u] = __builtin_amdgcn_mfma_f32_16x16x32_bf16(
                        af[t], bg[u], acc[t][u], 0, 0, 0);
        }
    }

    // epilogue: C/D layout col = lane&15 (n), row = quad*4+q (m)
    const int gm0 = bm * 128 + wm;
    const int gn0 = bn * BN + wn;
#pragma unroll
    for (int u = 0; u < NU; u++) {
        int gn = gn0 + u * 16 + r;
        float bv = (gn < biasN) ? bias[gn] : 0.0f;
#pragma unroll
        for (int t = 0; t < 2; t++) {
            int gm = gm0 + t * 16 + quad * 4;
#pragma unroll
            for (int q = 0; q < 4; q++) {
                float v2 = acc[t][u][q] + bv;
                if (OUT_BF16)
                    ((u16*)Cout)[(size_t)(gm + q) * N + gn] = f2bf(v2);
                else
                    ((float*)Cout)[(size_t)(gm + q) * N + gn] = v2;
            }
        }
    }
}

// ---------------- midA: fold + normalize + crop + GELU -> G (bf16 padded image) ----------------
// One block per (b', ch, quarter). Quarter s owns pixel rows [15s, 15s+15)
// (s=3: [45,66)) -- disjoint, all 66 rows covered. Loads the <=7 oy-rows that
// feed those pixel rows into LDS (coalesced), then column-strip threading:
// thread = (px = tid&127, row-parity = tid>>7). All px-dependent terms
// (kx validity, colterm = ox*49+kx, 1/cx) hoisted out of the row loop; all
// row-dependent terms (ky validity, row term, 1/cy) are wave-uniform (scalar).
// GELU applied once per pixel. No atomics, no divides, no per-gather index math.
__global__ __launch_bounds__(256) void midA_fold(const u16* __restrict__ hg,
                                                 u16* __restrict__ G) {
    __shared__ u16 sh[7 * OW * 49];    // 12348 u16 = 24696 B

    const int b  = blockIdx.x;
    const int bp = b / (NCH * 4);
    const int rr = b - bp * (NCH * 4);
    const int ch = rr >> 2;
    const int s  = rr & 3;
    const int lo    = (s == 0) ? 0 : (5 * s - 2);   // first loaded oy
    const int nload = (s == 0) ? 5 : 7;             // oy-rows loaded
    const int row0  = 15 * s;                       // first owned pixel row
    const int nrows = (s == 3) ? 21 : 15;           // owned pixel rows
    const int n0 = bp * LVEC;
    const int c0 = ch * 49;
    const int tid = threadIdx.x;

    // phase 0: coalesced load of nload token-rows x 49 channels
    for (int i = tid; i < nload * OW * 49; i += 256) {
        int l = i / 49, k = i - l * 49;
        sh[i] = hg[(size_t)(n0 + lo * OW + l) * HIDP + c0 + k];
    }
    __syncthreads();

    const int px = tid & 127;          // column owned by this thread
    const int rg = tid >> 7;           // row parity (wave-uniform)
    if (px >= WP) return;

    // hoisted px-side terms
    const bool pxin = (px >= 3) && (px <= 110);
    const int kx0 = px % 3;
    int  ct[3];
    bool vx[3];
    int  cx = 0;
#pragma unroll
    for (int dx = 0; dx < 3; dx++) {
        int kx = kx0 + 3 * dx, rx = px - kx;
        bool ok = pxin && (kx <= 6) && (rx >= 0) && (rx <= 105);
        vx[dx] = ok;
        ct[dx] = ok ? ((rx / 3) * 49 + kx) : 0;
        cx += ok ? 1 : 0;
    }
    const float fcx = (cx == 3) ? (1.0f / 3.0f) : ((cx == 2) ? 0.5f : 1.0f);

    u16* Gb = G + (size_t)(bp * NCH + ch) * (HP * WP);
    for (int ri = rg; ri < nrows; ri += 2) {
        int py = row0 + ri;            // wave-uniform
        float val = 0.0f;
        if (pxin && py >= 3 && py <= 62) {
            int ky0 = py % 3;
            float sum = 0.0f;
            int cy = 0;
#pragma unroll
            for (int dy = 0; dy < 3; dy++) {
                int ky = ky0 + 3 * dy, ry = py - ky;   // uniform
                if (ky <= 6 && ry >= 0 && ry <= 57) {  // uniform branch
                    int rt = (ry / 3 - lo) * (OW * 49) + ky * 7;
                    cy++;
                    float v0 = bf2f(sh[rt + ct[0]]);
                    float v1 = bf2f(sh[rt + ct[1]]);
                    float v2 = bf2f(sh[rt + ct[2]]);
                    sum += vx[0] ? v0 : 0.0f;
                    sum += vx[1] ? v1 : 0.0f;
                    sum += vx[2] ? v2 : 0.0f;
                }
            }
            float fcy = (cy == 3) ? (1.0f / 3.0f) : ((cy == 2) ? 0.5f : 1.0f);
            float m = sum * fcx * fcy;
            val = 0.5f * m * (1.0f + erff(m * 0.70710678118654752f));  // exact gelu
        }
        Gb[py * WP + px] = f2bf(val);
    }
}

// ---------------- midB: unfold (pure u16 gather), in place over hg ----------------
// One block per (b', ch, half). Reads only G (no hg reads) -> in-place write is
// safe. No float math: bf16 values copied through LDS verbatim.
__global__ __launch_bounds__(256) void midB_unfold(const u16* __restrict__ G,
                                                   u16* __restrict__ hg) {
    __shared__ u16 sG[34 * WP];        // 3876 u16 = 7752 B

    const int b  = blockIdx.x;
    const int bp = b / (NCH * 2);
    const int rr = b - bp * (NCH * 2);
    const int ch = rr >> 1;
    const int s  = rr & 1;
    const int o0 = s * 10;             // first owned oy
    const int n0 = bp * LVEC + o0 * OW;
    const int c0 = ch * 49;
    const int tid = threadIdx.x;

    const u16* Gb = G + (size_t)(bp * NCH + ch) * (HP * WP) + 3 * o0 * WP;
    for (int p = tid; p < 34 * WP; p += 256) sG[p] = Gb[p];
    __syncthreads();

    for (int i = tid; i < 10 * OW * 49; i += 256) {
        int l = i / 49, k = i - l * 49;     // l in [0,360)
        int ky = k / 7, kx = k - ky * 7;
        int oy = l / OW, ox = l - oy * OW;  // oy in [0,10)
        hg[(size_t)(n0 + l) * HIDP + c0 + k] = sG[(3 * oy + ky) * WP + kx + 3 * ox];
    }
}

// ---------------- launch ----------------
extern "C" void kernel_launch(void* const* d_in, const int* in_sizes, int n_in,
                              void* d_out, int out_size, void* d_ws, size_t ws_size,
                              hipStream_t stream) {
    (void)in_sizes; (void)n_in; (void)out_size; (void)ws_size;
    const float* x  = (const float*)d_in[0];
    const float* W1 = (const float*)d_in[1];
    const float* b1 = (const float*)d_in[2];
    const float* W2 = (const float*)d_in[3];
    const float* b2 = (const float*)d_in[4];
    float* out = (float*)d_out;

    char* ws = (char*)d_ws;
    u16* xb  = (u16*)(ws);                                   // 11520*512*2  = 11,796,480
    u16* W1b = (u16*)(ws + 11796480);                        // 2048*512*2   =  2,097,152
    u16* W2b = (u16*)(ws + 11796480 + 2097152);              // 512*2048*2   =  2,097,152
    u16* hg  = (u16*)(ws + 11796480 + 2097152 + 2097152);    // 11520*2048*2 = 47,185,920
    u16* G   = xb;   // xb is dead after GEMM1; G = 640*7524*2 = 9,630,720 B <= 11.8 MB

    // converts (single dispatch)
    cvt_all<<<CVT_XB + 2 * CVT_W1B, 256, 0, stream>>>(x, W1, W2, xb, W1b, W2b);

    // GEMM1: h = x @ W1^T + b1  -> bf16 (11520 x 2048, cols >=1960 are zero)
    gemm_bt<1, 128><<<(M_ROWS / 128) * (HIDP / 128), 512, 0, stream>>>(
        xb, W1b, b1, HID, (void*)hg, HIDP, DIM, DIM);

    // middle: fold/normalize/gelu -> G (overlaid on xb), then unfold in place
    midA_fold<<<BPRIME * NCH * 4, 256, 0, stream>>>(hg, G);
    midB_unfold<<<BPRIME * NCH * 2, 256, 0, stream>>>(G, hg);

    // GEMM2: out = g @ W2^T + b2 -> fp32 (11520 x 512), 128x64 tiles, K-loop
    // trimmed to 1984 (hg cols [1960,2048) are exactly zero).
    gemm_bt<0, 64><<<(M_ROWS / 128) * (DIM / 64), 512, 0, stream>>>(
        hg, W2b, b2, DIM, (void*)out, DIM, KP2, HIDP);
}

// Round 8
// 198.075 us; speedup vs baseline: 2.0330x; 1.0317x over previous
//
#include <hip/hip_runtime.h>
#include <cmath>

// ---------------- problem constants ----------------
#define M_ROWS   11520      // 2*5760
#define DIM      512
#define HID      1960
#define HIDP     2048       // padded HID (zeros)
#define KP2      1984       // GEMM2 K-loop bound: 31*64 >= HID, cols [1960,1984) are zero
#define OH       20
#define OW       36
#define LVEC     720        // OH*OW
#define NCH      40         // HID/49
#define BPRIME   16         // M_ROWS / LVEC
#define HP       66         // 60 + 2*3
#define WP       114        // 108 + 2*3

typedef unsigned short u16;
typedef __bf16 bf16x8 __attribute__((ext_vector_type(8)));
typedef float  f32x4  __attribute__((ext_vector_type(4)));

__device__ __forceinline__ u16 f2bf(float f) {
    unsigned u = __float_as_uint(f);
    u += 0x7fffu + ((u >> 16) & 1u);   // RNE
    return (u16)(u >> 16);
}
__device__ __forceinline__ float bf2f(u16 h) {
    return __uint_as_float(((unsigned)h) << 16);
}

__device__ __forceinline__ void gload_lds16(const void* g, void* l) {
    __builtin_amdgcn_global_load_lds(
        (const __attribute__((address_space(1))) void*)g,
        (__attribute__((address_space(3))) void*)l, 16, 0, 0);
}

// ---------------- fused fp32 -> bf16 converts + g2 pad-zeroing (one dispatch) ----------------
// blocks [0,5760): x; [5760,6784): W1 pad-rows; [6784,7808): W2 pad-cols;
// [7808,8078): zero g2 cols [1960,1984) (read by GEMM2's K-trim loop).
#define CVT_XB   5760
#define CVT_W1B  1024
#define CVT_W2B  1024
#define CVT_Z    270       // 11520 rows * 24 cols / (256*4)
__global__ __launch_bounds__(256) void cvt_all(const float* __restrict__ x,
                                               const float* __restrict__ W1,
                                               const float* __restrict__ W2,
                                               u16* __restrict__ xb,
                                               u16* __restrict__ W1b,
                                               u16* __restrict__ W2b,
                                               u16* __restrict__ g2) {
    const int b = blockIdx.x;
    const int tid = threadIdx.x;
    ushort4 o;
    if (b < CVT_XB) {
        int i = (b * 256 + tid) * 4;
        float4 v = *(const float4*)(x + i);
        o.x = f2bf(v.x); o.y = f2bf(v.y); o.z = f2bf(v.z); o.w = f2bf(v.w);
        *(ushort4*)(xb + i) = o;
    } else if (b < CVT_XB + CVT_W1B) {
        int i = ((b - CVT_XB) * 256 + tid) * 4;      // over 2048*512
        if (i < HID * DIM) {
            float4 v = *(const float4*)(W1 + i);
            o.x = f2bf(v.x); o.y = f2bf(v.y); o.z = f2bf(v.z); o.w = f2bf(v.w);
        } else {
            o.x = o.y = o.z = o.w = 0;
        }
        *(ushort4*)(W1b + i) = o;
    } else if (b < CVT_XB + CVT_W1B + CVT_W2B) {
        int i = ((b - CVT_XB - CVT_W1B) * 256 + tid) * 4;   // over 512*2048
        int d = i / HIDP, c = i - d * HIDP;
        if (c < HID) {
            float4 v = *(const float4*)(W2 + (size_t)d * HID + c);
            o.x = f2bf(v.x); o.y = f2bf(v.y); o.z = f2bf(v.z); o.w = f2bf(v.w);
        } else {
            o.x = o.y = o.z = o.w = 0;
        }
        *(ushort4*)(W2b + i) = o;
    } else {
        int i = ((b - CVT_XB - CVT_W1B - CVT_W2B) * 256 + tid) * 4;  // over 11520*24
        int row = i / 24, c = i - row * 24;
        o.x = o.y = o.z = o.w = 0;
        *(ushort4*)(g2 + (size_t)row * HIDP + HID + c) = o;
    }
}

// ---------------- bf16 NT-GEMM: C[m,n] = sum_k A[m,k]*B[n,k] + bias[n] ----------------
// 128(M) x BN(N) tile, BK=64, 512 threads = 8 waves (4 M x 2 N), each wave
// 32 x BN/2 via mfma_f32_16x16x32_bf16. LDS staged with global_load_lds
// width 16; XOR swizzle applied on the GLOBAL side (LDS dest is
// wave-uniform+lane*16) so ds_read_b128 is bank-conflict-free.
//
// XCD-locality block swizzle: hardware assigns XCD = blockIdx % 8 (round-robin).
// v = (blockIdx&7)*(NB/8) + (blockIdx>>3) gives each XCD a contiguous strip of
// bm values x all bn -> A-panels are fetched into ONE per-XCD L2 (not 8), and
// the B matrix (2 MB) stays L2-resident. Requires gridDim.x % 8 == 0.
template <int OUT_BF16, int BN>
__global__ __launch_bounds__(512) void gemm_bt(const u16* __restrict__ A,
                                               const u16* __restrict__ B,
                                               const float* __restrict__ bias,
                                               int biasN, void* __restrict__ Cout,
                                               int N, int K, int ldk) {
    constexpr int WN = BN / 2;       // wave N extent
    constexpr int NU = WN / 16;      // acc tiles along N (4 or 2)
    constexpr int BCH = BN * 8;      // B-tile 16B chunks (1024 or 512)

    __shared__ u16 sA[128 * 64];
    __shared__ u16 sB[BN * 64];

    const int tid  = threadIdx.x;
    const int ntn  = N / BN;
    const int NB   = gridDim.x;
    const int v    = (blockIdx.x & 7) * (NB >> 3) + (blockIdx.x >> 3);
    const int bm   = v / ntn;
    const int bn   = v - bm * ntn;
    const int lane = tid & 63;
    const int wv   = tid >> 6;       // 0..7
    const int wm   = (wv >> 1) * 32; // 4 wave-rows of 32
    const int wn   = (wv & 1) * WN;  // 2 wave-cols
    const int r    = lane & 15;
    const int quad = lane >> 4;

    const size_t Arow0 = (size_t)bm * 128 * ldk;
    const size_t Brow0 = (size_t)bn * BN * ldk;

    f32x4 acc[2][NU] = {};

    for (int kt = 0; kt < K; kt += 64) {
        __syncthreads();
#pragma unroll
        for (int i = 0; i < 2; i++) {          // A: 1024 chunks / 512 threads
            int e   = i * 512 + tid;
            int row = e >> 3;
            int cp  = e & 7;
            int cg  = cp ^ (row & 7);
            gload_lds16(A + Arow0 + (size_t)row * ldk + kt + cg * 8, (char*)sA + e * 16);
        }
#pragma unroll
        for (int i = 0; i < BCH / 512; i++) {  // B: BCH chunks / 512 threads
            int e   = i * 512 + tid;
            int row = e >> 3;
            int cp  = e & 7;
            int cg  = cp ^ (row & 7);
            gload_lds16(B + Brow0 + (size_t)row * ldk + kt + cg * 8, (char*)sB + e * 16);
        }
        __syncthreads();
#pragma unroll
        for (int kk = 0; kk < 2; kk++) {
            bf16x8 af[2], bg[NU];
#pragma unroll
            for (int t = 0; t < 2; t++) {
                int row = wm + t * 16 + r;
                int c   = (kk * 4 + quad) ^ (row & 7);
                af[t] = *(const bf16x8*)(sA + row * 64 + c * 8);
            }
#pragma unroll
            for (int u = 0; u < NU; u++) {
                int row = wn + u * 16 + r;
                int c   = (kk * 4 + quad) ^ (row & 7);
                bg[u] = *(const bf16x8*)(sB + row * 64 + c * 8);
            }
#pragma unroll
            for (int t = 0; t < 2; t++)
#pragma unroll
                for (int u = 0; u < NU; u++)
                    acc[t][u] = __builtin_amdgcn_mfma_f32_16x16x32_bf16(
                        af[t], bg[u], acc[t][u], 0, 0, 0);
        }
    }

    // epilogue: C/D layout col = lane&15 (n), row = quad*4+q (m)
    const int gm0 = bm * 128 + wm;
    const int gn0 = bn * BN + wn;
#pragma unroll
    for (int u = 0; u < NU; u++) {
        int gn = gn0 + u * 16 + r;
        float bv = (gn < biasN) ? bias[gn] : 0.0f;
#pragma unroll
        for (int t = 0; t < 2; t++) {
            int gm = gm0 + t * 16 + quad * 4;
#pragma unroll
            for (int q = 0; q < 4; q++) {
                float v2 = acc[t][u][q] + bv;
                if (OUT_BF16)
                    ((u16*)Cout)[(size_t)(gm + q) * N + gn] = f2bf(v2);
                else
                    ((float*)Cout)[(size_t)(gm + q) * N + gn] = v2;
            }
        }
    }
}

// ---------------- mid: fold + normalize + crop + GELU + unfold, fully fused ----------------
// One block per (b', ch, half). Half s owns oy rows [10s, 10s+10) and needs G
// pixel rows [30s, 30s+34); those depend on h oy-rows [8s, 8s+12).
// phase0: load 12 oy-rows of h -> LDS (read-only; output goes to g2, so no
//         cross-block in-place hazard).
// phase1: compute the 34 G rows into LDS (column-strip threading: px = tid&127,
//         row-group = tid>>7 wave-uniform; kx-side terms hoisted; gelu once per
//         pixel). G never touches global memory.
// phase2: unfold from LDS G -> g2 (coalesced 49-col groups).
__global__ __launch_bounds__(512) void mid_fused(const u16* __restrict__ hg,
                                                 u16* __restrict__ g2) {
    __shared__ u16 sh[12 * OW * 49];   // 21168 u16 = 42336 B
    __shared__ u16 sG[34 * WP];        //  3876 u16 =  7752 B

    const int b  = blockIdx.x;
    const int bp = b / (NCH * 2);
    const int rr = b - bp * (NCH * 2);
    const int ch = rr >> 1;
    const int s  = rr & 1;
    const int o0 = s * 10;             // first owned oy
    const int lo = s * 8;              // first loaded oy
    const int n0 = bp * LVEC;
    const int c0 = ch * 49;
    const int tid = threadIdx.x;

    // phase 0: coalesced load of 12 token-rows x 49 channels
    for (int i = tid; i < 12 * OW * 49; i += 512) {
        int l = i / 49, k = i - l * 49;
        sh[i] = hg[(size_t)(n0 + lo * OW + l) * HIDP + c0 + k];
    }
    __syncthreads();

    // phase 1: G rows [3*o0, 3*o0+34) -> sG
    const int px = tid & 127;
    const int rg = tid >> 7;           // 0..3, wave-uniform (2 waves per rg)
    if (px < WP) {
        const bool pxin = (px >= 3) && (px <= 110);
        const int kx0 = px % 3;
        int  ct[3];
        bool vx[3];
        int  cx = 0;
#pragma unroll
        for (int dx = 0; dx < 3; dx++) {
            int kx = kx0 + 3 * dx, rx = px - kx;
            bool ok = pxin && (kx <= 6) && (rx >= 0) && (rx <= 105);
            vx[dx] = ok;
            ct[dx] = ok ? ((rx / 3) * 49 + kx) : 0;
            cx += ok ? 1 : 0;
        }
        const float fcx = (cx == 3) ? (1.0f / 3.0f) : ((cx == 2) ? 0.5f : 1.0f);

        for (int pr = rg; pr < 34; pr += 4) {
            int py = 3 * o0 + pr;      // wave-uniform
            float val = 0.0f;
            if (pxin && py >= 3 && py <= 62) {
                int ky0 = py % 3;
                float sum = 0.0f;
                int cy = 0;
#pragma unroll
                for (int dy = 0; dy < 3; dy++) {
                    int ky = ky0 + 3 * dy, ry = py - ky;   // uniform
                    if (ky <= 6 && ry >= 0 && ry <= 57) {  // uniform branch
                        int rt = (ry / 3 - lo) * (OW * 49) + ky * 7;
                        cy++;
                        float v0 = bf2f(sh[rt + ct[0]]);
                        float v1 = bf2f(sh[rt + ct[1]]);
                        float v2 = bf2f(sh[rt + ct[2]]);
                        sum += vx[0] ? v0 : 0.0f;
                        sum += vx[1] ? v1 : 0.0f;
                        sum += vx[2] ? v2 : 0.0f;
                    }
                }
                float fcy = (cy == 3) ? (1.0f / 3.0f) : ((cy == 2) ? 0.5f : 1.0f);
                float m = sum * fcx * fcy;
                val = 0.5f * m * (1.0f + erff(m * 0.70710678118654752f));  // exact gelu
            }
            sG[pr * WP + px] = f2bf(val);
        }
    }
    __syncthreads();

    // phase 2: unfold from sG -> g2 (10 owned oy rows)
    const int nb = (n0 + o0 * OW);
    for (int i = tid; i < 10 * OW * 49; i += 512) {
        int l = i / 49, k = i - l * 49;     // l in [0,360)
        int ky = k / 7, kx = k - ky * 7;
        int oy = l / OW, ox = l - oy * OW;  // oy in [0,10)
        g2[(size_t)(nb + l) * HIDP + c0 + k] = sG[(3 * oy + ky) * WP + kx + 3 * ox];
    }
}

// ---------------- launch ----------------
extern "C" void kernel_launch(void* const* d_in, const int* in_sizes, int n_in,
                              void* d_out, int out_size, void* d_ws, size_t ws_size,
                              hipStream_t stream) {
    (void)in_sizes; (void)n_in; (void)out_size; (void)ws_size;
    const float* x  = (const float*)d_in[0];
    const float* W1 = (const float*)d_in[1];
    const float* b1 = (const float*)d_in[2];
    const float* W2 = (const float*)d_in[3];
    const float* b2 = (const float*)d_in[4];
    float* out = (float*)d_out;

    char* ws = (char*)d_ws;
    u16* xb  = (u16*)(ws);                       // 11520*512*2  = 11,796,480
    u16* W1b = (u16*)(ws + 11796480);            // 2048*512*2   =  2,097,152
    u16* W2b = (u16*)(ws + 13893632);            // 512*2048*2   =  2,097,152
    u16* hg  = (u16*)(ws + 15990784);            // 11520*2048*2 = 47,185,920
    u16* g2  = (u16*)(ws + 63176704);            // 11520*2048*2 = 47,185,920 (total 110 MB)

    // converts + g2 pad-zeroing (single dispatch)
    cvt_all<<<CVT_XB + CVT_W1B + CVT_W2B + CVT_Z, 256, 0, stream>>>(
        x, W1, W2, xb, W1b, W2b, g2);

    // GEMM1: h = x @ W1^T + b1  -> bf16 (11520 x 2048, cols >=1960 are zero)
    gemm_bt<1, 128><<<(M_ROWS / 128) * (HIDP / 128), 512, 0, stream>>>(
        xb, W1b, b1, HID, (void*)hg, HIDP, DIM, DIM);

    // middle: fold/normalize/gelu/unfold fused, hg -> g2 (G stays in LDS)
    mid_fused<<<BPRIME * NCH * 2, 512, 0, stream>>>(hg, g2);

    // GEMM2: out = g2 @ W2^T + b2 -> fp32 (11520 x 512), 128x64 tiles, K-loop
    // trimmed to 1984 (g2 cols [1960,1984) zero-filled by cvt_all).
    gemm_bt<0, 64><<<(M_ROWS / 128) * (DIM / 64), 512, 0, stream>>>(
        g2, W2b, b2, DIM, (void*)out, DIM, KP2, HIDP);
}

// Round 9
// 186.320 us; speedup vs baseline: 2.1612x; 1.0631x over previous
//
#include <hip/hip_runtime.h>
#include <cmath>

// ---------------- problem constants ----------------
#define M_ROWS   11520      // 2*5760
#define DIM      512
#define HID      1960
#define HIDP     2048       // padded HID (zeros)
#define KP2      1984       // GEMM2 K-loop bound: 31*64 >= HID, cols [1960,1984) are zero
#define OH       20
#define OW       36
#define LVEC     720        // OH*OW
#define NCH      40         // HID/49
#define BPRIME   16         // M_ROWS / LVEC
#define HP       66         // 60 + 2*3
#define WP       114        // 108 + 2*3

typedef unsigned short u16;
typedef __bf16 bf16x8 __attribute__((ext_vector_type(8)));
typedef float  f32x4  __attribute__((ext_vector_type(4)));

__device__ __forceinline__ u16 f2bf(float f) {
    unsigned u = __float_as_uint(f);
    u += 0x7fffu + ((u >> 16) & 1u);   // RNE
    return (u16)(u >> 16);
}
__device__ __forceinline__ float bf2f(u16 h) {
    return __uint_as_float(((unsigned)h) << 16);
}

__device__ __forceinline__ void gload_lds16(const void* g, void* l) {
    __builtin_amdgcn_global_load_lds(
        (const __attribute__((address_space(1))) void*)g,
        (__attribute__((address_space(3))) void*)l, 16, 0, 0);
}
__device__ __forceinline__ void gload_lds4(const void* g, void* l) {
    __builtin_amdgcn_global_load_lds(
        (const __attribute__((address_space(1))) void*)g,
        (__attribute__((address_space(3))) void*)l, 4, 0, 0);
}

// ---------------- fused fp32 -> bf16 converts + g2 pad-zeroing (one dispatch) ----------------
// blocks [0,5760): x; [5760,6784): W1 pad-rows; [6784,7808): W2 pad-cols;
// [7808,8078): zero g2 cols [1960,1984) (read by GEMM2's K-trim loop).
#define CVT_XB   5760
#define CVT_W1B  1024
#define CVT_W2B  1024
#define CVT_Z    270       // 11520 rows * 24 cols / (256*4)
__global__ __launch_bounds__(256) void cvt_all(const float* __restrict__ x,
                                               const float* __restrict__ W1,
                                               const float* __restrict__ W2,
                                               u16* __restrict__ xb,
                                               u16* __restrict__ W1b,
                                               u16* __restrict__ W2b,
                                               u16* __restrict__ g2) {
    const int b = blockIdx.x;
    const int tid = threadIdx.x;
    ushort4 o;
    if (b < CVT_XB) {
        int i = (b * 256 + tid) * 4;
        float4 v = *(const float4*)(x + i);
        o.x = f2bf(v.x); o.y = f2bf(v.y); o.z = f2bf(v.z); o.w = f2bf(v.w);
        *(ushort4*)(xb + i) = o;
    } else if (b < CVT_XB + CVT_W1B) {
        int i = ((b - CVT_XB) * 256 + tid) * 4;      // over 2048*512
        if (i < HID * DIM) {
            float4 v = *(const float4*)(W1 + i);
            o.x = f2bf(v.x); o.y = f2bf(v.y); o.z = f2bf(v.z); o.w = f2bf(v.w);
        } else {
            o.x = o.y = o.z = o.w = 0;
        }
        *(ushort4*)(W1b + i) = o;
    } else if (b < CVT_XB + CVT_W1B + CVT_W2B) {
        int i = ((b - CVT_XB - CVT_W1B) * 256 + tid) * 4;   // over 512*2048
        int d = i / HIDP, c = i - d * HIDP;
        if (c < HID) {
            float4 v = *(const float4*)(W2 + (size_t)d * HID + c);
            o.x = f2bf(v.x); o.y = f2bf(v.y); o.z = f2bf(v.z); o.w = f2bf(v.w);
        } else {
            o.x = o.y = o.z = o.w = 0;
        }
        *(ushort4*)(W2b + i) = o;
    } else {
        int i = ((b - CVT_XB - CVT_W1B - CVT_W2B) * 256 + tid) * 4;  // over 11520*24
        int row = i / 24, c = i - row * 24;
        o.x = o.y = o.z = o.w = 0;
        *(ushort4*)(g2 + (size_t)row * HIDP + HID + c) = o;
    }
}

// ---------------- bf16 NT-GEMM: C[m,n] = sum_k A[m,k]*B[n,k] + bias[n] ----------------
// 128(M) x BN(N) tile, BK=64, 512 threads = 8 waves (4 M x 2 N), each wave
// 32 x BN/2 via mfma_f32_16x16x32_bf16. LDS staged with global_load_lds
// width 16; XOR swizzle applied on the GLOBAL side (LDS dest is
// wave-uniform+lane*16) so ds_read_b128 is bank-conflict-free.
//
// XCD-locality block swizzle: hardware assigns XCD = blockIdx % 8 (round-robin).
// v = (blockIdx&7)*(NB/8) + (blockIdx>>3) gives each XCD a contiguous strip of
// bm values x all bn -> A-panels are fetched into ONE per-XCD L2 (not 8), and
// the B matrix (2 MB) stays L2-resident. Requires gridDim.x % 8 == 0.
template <int OUT_BF16, int BN>
__global__ __launch_bounds__(512) void gemm_bt(const u16* __restrict__ A,
                                               const u16* __restrict__ B,
                                               const float* __restrict__ bias,
                                               int biasN, void* __restrict__ Cout,
                                               int N, int K, int ldk) {
    constexpr int WN = BN / 2;       // wave N extent
    constexpr int NU = WN / 16;      // acc tiles along N (4 or 2)
    constexpr int BCH = BN * 8;      // B-tile 16B chunks (1024 or 512)

    __shared__ u16 sA[128 * 64];
    __shared__ u16 sB[BN * 64];

    const int tid  = threadIdx.x;
    const int ntn  = N / BN;
    const int NB   = gridDim.x;
    const int v    = (blockIdx.x & 7) * (NB >> 3) + (blockIdx.x >> 3);
    const int bm   = v / ntn;
    const int bn   = v - bm * ntn;
    const int lane = tid & 63;
    const int wv   = tid >> 6;       // 0..7
    const int wm   = (wv >> 1) * 32; // 4 wave-rows of 32
    const int wn   = (wv & 1) * WN;  // 2 wave-cols
    const int r    = lane & 15;
    const int quad = lane >> 4;

    const size_t Arow0 = (size_t)bm * 128 * ldk;
    const size_t Brow0 = (size_t)bn * BN * ldk;

    f32x4 acc[2][NU] = {};

    for (int kt = 0; kt < K; kt += 64) {
        __syncthreads();
#pragma unroll
        for (int i = 0; i < 2; i++) {          // A: 1024 chunks / 512 threads
            int e   = i * 512 + tid;
            int row = e >> 3;
            int cp  = e & 7;
            int cg  = cp ^ (row & 7);
            gload_lds16(A + Arow0 + (size_t)row * ldk + kt + cg * 8, (char*)sA + e * 16);
        }
#pragma unroll
        for (int i = 0; i < BCH / 512; i++) {  // B: BCH chunks / 512 threads
            int e   = i * 512 + tid;
            int row = e >> 3;
            int cp  = e & 7;
            int cg  = cp ^ (row & 7);
            gload_lds16(B + Brow0 + (size_t)row * ldk + kt + cg * 8, (char*)sB + e * 16);
        }
        __syncthreads();
#pragma unroll
        for (int kk = 0; kk < 2; kk++) {
            bf16x8 af[2], bg[NU];
#pragma unroll
            for (int t = 0; t < 2; t++) {
                int row = wm + t * 16 + r;
                int c   = (kk * 4 + quad) ^ (row & 7);
                af[t] = *(const bf16x8*)(sA + row * 64 + c * 8);
            }
#pragma unroll
            for (int u = 0; u < NU; u++) {
                int row = wn + u * 16 + r;
                int c   = (kk * 4 + quad) ^ (row & 7);
                bg[u] = *(const bf16x8*)(sB + row * 64 + c * 8);
            }
#pragma unroll
            for (int t = 0; t < 2; t++)
#pragma unroll
                for (int u = 0; u < NU; u++)
                    acc[t][u] = __builtin_amdgcn_mfma_f32_16x16x32_bf16(
                        af[t], bg[u], acc[t][u], 0, 0, 0);
        }
    }

    // epilogue: C/D layout col = lane&15 (n), row = quad*4+q (m)
    const int gm0 = bm * 128 + wm;
    const int gn0 = bn * BN + wn;
#pragma unroll
    for (int u = 0; u < NU; u++) {
        int gn = gn0 + u * 16 + r;
        float bv = (gn < biasN) ? bias[gn] : 0.0f;
#pragma unroll
        for (int t = 0; t < 2; t++) {
            int gm = gm0 + t * 16 + quad * 4;
#pragma unroll
            for (int q = 0; q < 4; q++) {
                float v2 = acc[t][u][q] + bv;
                if (OUT_BF16)
                    ((u16*)Cout)[(size_t)(gm + q) * N + gn] = f2bf(v2);
                else
                    ((float*)Cout)[(size_t)(gm + q) * N + gn] = v2;
            }
        }
    }
}

// ---------------- mid: fold + normalize + crop + GELU + unfold, fully fused ----------------
// One block per (b', ch, half). Half s owns oy rows [10s, 10s+10); needs G pixel
// rows [30s, 30s+34), which depend on h oy-rows [8s, 8s+12).
// phase0: 12 oy-rows of h -> LDS via global_load_lds width-4 (u32-aligned by
//         rounding the channel base down to c0e = c0 & ~1; 50 u16 per row).
// phase1: 34 G rows into LDS (column-strip threading, hoisted kx terms, gelu
//         once per pixel). G never touches global memory.
// phase2: unfold sG -> g2 with LUT-based indexing (rowoff[360], kidx[49]) and
//         incremental l/k/store-offset updates -- no per-element divides.
__global__ __launch_bounds__(512) void mid_fused(const u16* __restrict__ hg,
                                                 u16* __restrict__ g2) {
    __shared__ u16 sh[12 * OW * 50];   // 21600 u16 = 43200 B (50 u16/row, u32-aligned)
    __shared__ u16 sG[34 * WP];        //  3876 u16 =  7752 B
    __shared__ u16 rowoff[10 * OW];    //   360 u16 (342*oy + 3*ox)
    __shared__ u16 kidx[49];           //    49 u16 (114*ky + kx)

    const int b  = blockIdx.x;
    const int bp = b / (NCH * 2);
    const int rr = b - bp * (NCH * 2);
    const int ch = rr >> 1;
    const int s  = rr & 1;
    const int o0 = s * 10;             // first owned oy
    const int lo = s * 8;              // first loaded oy
    const int n0 = bp * LVEC;
    const int c0 = ch * 49;
    const int c0e = c0 & ~1;           // u32-aligned channel base
    const int koff = c0 - c0e;         // 0 or 1
    const int tid = threadIdx.x;

    // LUT build (independent of phase-0 loads; covered by the same barrier)
    if (tid < 10 * OW) {
        int oy = tid / OW, ox = tid - oy * OW;
        rowoff[tid] = (u16)(342 * oy + 3 * ox);
    } else if (tid < 10 * OW + 49) {
        int k = tid - 10 * OW;
        int ky = k / 7;
        kidx[k] = (u16)(114 * ky + (k - 7 * ky));
    }

    // phase 0: 12 rows x 25 u32 chunks, DMA'd straight to LDS.
    // chunk i -> row l = i/25, slot j = i%25; LDS dest = sh bytes [i*4, i*4+4)
    // == sh_u16[l*50 + 2j ..] exactly (50 u16 per row).
    {
        const char* hb = (const char*)(hg + (size_t)(n0 + lo * OW) * HIDP + c0e);
        for (int i = tid; i < 12 * OW * 25; i += 512) {
            int l = i / 25, j = i - l * 25;
            gload_lds4(hb + (size_t)l * (HIDP * 2) + j * 4, (char*)sh + i * 4);
        }
    }
    __syncthreads();

    // phase 1: G rows [3*o0, 3*o0+34) -> sG
    const int px = tid & 127;
    const int rg = tid >> 7;           // 0..3, wave-uniform (2 waves per rg)
    if (px < WP) {
        const bool pxin = (px >= 3) && (px <= 110);
        const int kx0 = px % 3;
        int  ct[3];
        bool vx[3];
        int  cx = 0;
#pragma unroll
        for (int dx = 0; dx < 3; dx++) {
            int kx = kx0 + 3 * dx, rx = px - kx;
            bool ok = pxin && (kx <= 6) && (rx >= 0) && (rx <= 105);
            vx[dx] = ok;
            ct[dx] = ok ? ((rx / 3) * 50 + kx) : 0;
            cx += ok ? 1 : 0;
        }
        const float fcx = (cx == 3) ? (1.0f / 3.0f) : ((cx == 2) ? 0.5f : 1.0f);

        for (int pr = rg; pr < 34; pr += 4) {
            int py = 3 * o0 + pr;      // wave-uniform
            float val = 0.0f;
            if (pxin && py >= 3 && py <= 62) {
                int ky0 = py % 3;
                float sum = 0.0f;
                int cy = 0;
#pragma unroll
                for (int dy = 0; dy < 3; dy++) {
                    int ky = ky0 + 3 * dy, ry = py - ky;   // uniform
                    if (ky <= 6 && ry >= 0 && ry <= 57) {  // uniform branch
                        int rt = (ry / 3 - lo) * (OW * 50) + ky * 7 + koff;
                        cy++;
                        float v0 = bf2f(sh[rt + ct[0]]);
                        float v1 = bf2f(sh[rt + ct[1]]);
                        float v2 = bf2f(sh[rt + ct[2]]);
                        sum += vx[0] ? v0 : 0.0f;
                        sum += vx[1] ? v1 : 0.0f;
                        sum += vx[2] ? v2 : 0.0f;
                    }
                }
                float fcy = (cy == 3) ? (1.0f / 3.0f) : ((cy == 2) ? 0.5f : 1.0f);
                float m = sum * fcx * fcy;
                val = 0.5f * m * (1.0f + erff(m * 0.70710678118654752f));  // exact gelu
            }
            sG[pr * WP + px] = f2bf(val);
        }
    }
    __syncthreads();

    // phase 2: unfold sG -> g2, LUT indices + incremental l/k updates.
    // i = l*49 + k; i += 512 == l += 10, k += 22 (wrap: k -= 49, l += 1).
    {
        u16* g2row = g2 + (size_t)(n0 + o0 * OW) * HIDP + c0;
        int l = tid / 49;
        int k = tid - l * 49;
        int soff = l * HIDP + k;                 // store offset (elements)
        for (int i = tid; i < 10 * OW * 49; i += 512) {
            g2row[soff] = sG[rowoff[l] + kidx[k]];
            l += 10; k += 22; soff += 10 * HIDP + 22;
            if (k >= 49) { k -= 49; l += 1; soff += HIDP - 49; }
        }
    }
}

// ---------------- launch ----------------
extern "C" void kernel_launch(void* const* d_in, const int* in_sizes, int n_in,
                              void* d_out, int out_size, void* d_ws, size_t ws_size,
                              hipStream_t stream) {
    (void)in_sizes; (void)n_in; (void)out_size; (void)ws_size;
    const float* x  = (const float*)d_in[0];
    const float* W1 = (const float*)d_in[1];
    const float* b1 = (const float*)d_in[2];
    const float* W2 = (const float*)d_in[3];
    const float* b2 = (const float*)d_in[4];
    float* out = (float*)d_out;

    char* ws = (char*)d_ws;
    u16* xb  = (u16*)(ws);                       // 11520*512*2  = 11,796,480
    u16* W1b = (u16*)(ws + 11796480);            // 2048*512*2   =  2,097,152
    u16* W2b = (u16*)(ws + 13893632);            // 512*2048*2   =  2,097,152
    u16* hg  = (u16*)(ws + 15990784);            // 11520*2048*2 = 47,185,920
    u16* g2  = (u16*)(ws + 63176704);            // 11520*2048*2 = 47,185,920 (total 110 MB)

    // converts + g2 pad-zeroing (single dispatch)
    cvt_all<<<CVT_XB + CVT_W1B + CVT_W2B + CVT_Z, 256, 0, stream>>>(
        x, W1, W2, xb, W1b, W2b, g2);

    // GEMM1: h = x @ W1^T + b1  -> bf16 (11520 x 2048, cols >=1960 are zero)
    gemm_bt<1, 128><<<(M_ROWS / 128) * (HIDP / 128), 512, 0, stream>>>(
        xb, W1b, b1, HID, (void*)hg, HIDP, DIM, DIM);

    // middle: fold/normalize/gelu/unfold fused, hg -> g2 (G stays in LDS)
    mid_fused<<<BPRIME * NCH * 2, 512, 0, stream>>>(hg, g2);

    // GEMM2: out = g2 @ W2^T + b2 -> fp32 (11520 x 512), 128x64 tiles, K-loop
    // trimmed to 1984 (g2 cols [1960,1984) zero-filled by cvt_all).
    gemm_bt<0, 64><<<(M_ROWS / 128) * (DIM / 64), 512, 0, stream>>>(
        g2, W2b, b2, DIM, (void*)out, DIM, KP2, HIDP);
}